// Round 1
// baseline (636.511 us; speedup 1.0000x reference)
//
#include <hip/hip_runtime.h>

#define D 16
#define EFD 8
#define TROW 272   // 256 T values (j*16+o) + 16 bias-projection values B[o]

// ---------------- preprocessing: counting sort of edges by dst ----------------

__global__ void k_zero_i(int* p, int n) {
    int i = blockIdx.x * 256 + threadIdx.x;
    if (i < n) p[i] = 0;
}

__global__ void k_hist(const int* __restrict__ dst, int* __restrict__ cnt, int E_) {
    int e = blockIdx.x * 256 + threadIdx.x;
    if (e < E_) atomicAdd(&cnt[dst[e]], 1);
}

__global__ void k_scanA(const int* __restrict__ cnt, int* __restrict__ offs,
                        int* __restrict__ bsum, int n) {
    __shared__ int s[1024];
    int i = blockIdx.x * 1024 + threadIdx.x;
    int v = (i < n) ? cnt[i] : 0;
    s[threadIdx.x] = v;
    __syncthreads();
    for (int d = 1; d < 1024; d <<= 1) {
        int t = (threadIdx.x >= d) ? s[threadIdx.x - d] : 0;
        __syncthreads();
        s[threadIdx.x] += t;
        __syncthreads();
    }
    int incl = s[threadIdx.x];
    if (i < n) offs[i] = incl - v;          // exclusive within chunk
    if (threadIdx.x == 1023) bsum[blockIdx.x] = incl;
}

__global__ void k_scanB(int* bsum, int nb) {
    __shared__ int s[64];
    int v = (threadIdx.x < nb) ? bsum[threadIdx.x] : 0;
    s[threadIdx.x] = v;
    __syncthreads();
    for (int d = 1; d < 64; d <<= 1) {
        int t = (threadIdx.x >= d) ? s[threadIdx.x - d] : 0;
        __syncthreads();
        s[threadIdx.x] += t;
        __syncthreads();
    }
    if (threadIdx.x < nb) bsum[threadIdx.x] = s[threadIdx.x] - v;  // exclusive
}

__global__ void k_scanC(int* __restrict__ offs, int* __restrict__ cursor,
                        const int* __restrict__ bsum, int n, int total) {
    int i = blockIdx.x * 1024 + threadIdx.x;
    if (i < n) {
        int v = offs[i] + bsum[blockIdx.x];
        offs[i] = v;
        cursor[i] = v;
    } else if (i == n) {
        offs[n] = total;
    }
}

__global__ void k_scatter(const int* __restrict__ src, const int* __restrict__ dst,
                          int* __restrict__ cursor, int* __restrict__ srcS,
                          int* __restrict__ eidS, int E_) {
    int e = blockIdx.x * 256 + threadIdx.x;
    if (e < E_) {
        int p = atomicAdd(&cursor[dst[e]], 1);
        srcS[p] = src[e];
        eidS[p] = e;
    }
}

// ---------------- edge MLP layer 1 (shared across conv layers), stored dst-sorted ----------------

__global__ void k_he(const float* __restrict__ ea, const float* __restrict__ w1,
                     const float* __restrict__ b1, const int* __restrict__ eidS,
                     float* __restrict__ hE, int E_) {
    __shared__ float w1s[EFD * D];
    if (threadIdx.x < EFD * D) w1s[threadIdx.x] = w1[threadIdx.x];
    __syncthreads();
    int t = blockIdx.x * 256 + threadIdx.x;
    int p = t >> 4, o = t & 15;
    if (p < E_) {
        int e = eidS[p];
        const float* a = ea + (size_t)e * EFD;
        float s = b1[o];
#pragma unroll
        for (int k = 0; k < EFD; k++) s += a[k] * w1s[k * D + o];
        hE[(size_t)p * D + o] = tanhf(s);
    }
}

// ---------------- per-layer: node precompute T[n,j,o] = sum_i h[n,i]*w2[j,i*16+o] ----------------

__global__ void k_T(const float* __restrict__ h, const float* __restrict__ w2,
                    const float* __restrict__ b2, float* __restrict__ T,
                    float* __restrict__ stats, int n) {
    __shared__ float hs[D];
    int node = blockIdx.x;
    if (threadIdx.x < D) hs[threadIdx.x] = h[(size_t)node * D + threadIdx.x];
    if (blockIdx.x == 0 && threadIdx.x < 32) stats[threadIdx.x] = 0.f;  // zero BN stats
    __syncthreads();
    int c = threadIdx.x;  // block = 272 threads
    float s = 0.f;
    if (c < 256) {
        int j = c >> 4, o = c & 15;
#pragma unroll
        for (int i = 0; i < D; i++) s += hs[i] * w2[j * 256 + i * D + o];
    } else {
        int o = c - 256;
#pragma unroll
        for (int i = 0; i < D; i++) s += hs[i] * b2[i * D + o];
    }
    T[(size_t)node * TROW + c] = s;
}

// ---------------- per-layer: NNConv aggregation + root + bias, block = 16 nodes x 16 ch ----------------

__global__ void k_conv(const float* __restrict__ h, const float* __restrict__ T,
                       const float* __restrict__ hE, const int* __restrict__ srcS,
                       const int* __restrict__ offs, const float* __restrict__ root_l,
                       const float* __restrict__ cbias, float* __restrict__ hpre,
                       float* __restrict__ stats, int n) {
    __shared__ float rootS[D * D];
    __shared__ float red[256], red2[256];
    if (threadIdx.x < D * D) rootS[threadIdx.x] = root_l[threadIdx.x];
    __syncthreads();
    int slot = threadIdx.x >> 4, o = threadIdx.x & 15;
    int node = blockIdx.x * 16 + slot;
    float acc = 0.f;
    if (node < n) {
        int p0 = offs[node], p1 = offs[node + 1];
        float sum = 0.f;
        for (int p = p0; p < p1; p++) {
            int s = srcS[p];
            const float* Trow = T + (size_t)s * TROW;
            const float* he = hE + (size_t)p * D;
            float a = Trow[256 + o];
#pragma unroll
            for (int j = 0; j < D; j++) a += he[j] * Trow[j * D + o];
            sum += a;
        }
        float deg = (float)((p1 - p0) > 1 ? (p1 - p0) : 1);
        float r = cbias[o];
        const float* hr = h + (size_t)node * D;
#pragma unroll
        for (int i = 0; i < D; i++) r += hr[i] * rootS[i * D + o];
        acc = sum / deg + r;
        hpre[(size_t)node * D + o] = acc;
    }
    // BN partial stats: reduce across the 16 node-slots (channel preserved mod 16)
    red[threadIdx.x] = acc;
    red2[threadIdx.x] = acc * acc;
    __syncthreads();
    for (int off = 128; off >= 16; off >>= 1) {
        if (threadIdx.x < off) {
            red[threadIdx.x] += red[threadIdx.x + off];
            red2[threadIdx.x] += red2[threadIdx.x + off];
        }
        __syncthreads();
    }
    if (threadIdx.x < 16) {
        atomicAdd(&stats[threadIdx.x], red[threadIdx.x]);
        atomicAdd(&stats[16 + threadIdx.x], red2[threadIdx.x]);
    }
}

// ---------------- per-layer: BatchNorm apply + tanh ----------------

__global__ void k_bn(const float* __restrict__ hpre, const float* __restrict__ stats,
                     const float* __restrict__ gamma, const float* __restrict__ beta,
                     float* __restrict__ out, int n) {
    int i = blockIdx.x * 256 + threadIdx.x;
    if (i < n * D) {
        int o = i & 15;
        float fn = (float)n;
        float mu = stats[o] / fn;
        float var = stats[16 + o] / fn - mu * mu;
        float x = hpre[i];
        float y = (x - mu) * rsqrtf(var + 1e-5f) * gamma[o] + beta[o];
        out[i] = tanhf(y);
    }
}

// ---------------- readout: graph offsets, pooling, MLP + log_softmax ----------------

__global__ void k_gscan(const int* __restrict__ lengths, int* __restrict__ goffs, int Gc) {
    __shared__ int s[512];
    int v = (threadIdx.x < Gc) ? lengths[threadIdx.x] : 0;
    s[threadIdx.x] = v;
    __syncthreads();
    for (int d = 1; d < 512; d <<= 1) {
        int t = (threadIdx.x >= d) ? s[threadIdx.x - d] : 0;
        __syncthreads();
        s[threadIdx.x] += t;
        __syncthreads();
    }
    if (threadIdx.x < Gc) goffs[threadIdx.x] = s[threadIdx.x] - v;
    if (threadIdx.x == Gc - 1) goffs[Gc] = s[threadIdx.x];
}

__global__ void k_pool(const float* __restrict__ hidden, const int* __restrict__ goffs,
                       float* __restrict__ pooled, int Gc) {
    int g = blockIdx.x;
    int slot = threadIdx.x >> 4, o = threadIdx.x & 15;  // 4 slots x 16 ch
    int n0 = goffs[g], n1 = goffs[g + 1];
    float s = 0.f, mx = -3.402823466e38f, mn = 3.402823466e38f;
    for (int nd = n0 + slot; nd < n1; nd += 4) {
        float v = hidden[(size_t)nd * D + o];
        s += v;
        mx = fmaxf(mx, v);
        mn = fminf(mn, v);
    }
    __shared__ float rs[64], rmx[64], rmn[64];
    rs[threadIdx.x] = s; rmx[threadIdx.x] = mx; rmn[threadIdx.x] = mn;
    __syncthreads();
    for (int off = 32; off >= 16; off >>= 1) {
        if (threadIdx.x < off) {
            rs[threadIdx.x] += rs[threadIdx.x + off];
            rmx[threadIdx.x] = fmaxf(rmx[threadIdx.x], rmx[threadIdx.x + off]);
            rmn[threadIdx.x] = fminf(rmn[threadIdx.x], rmn[threadIdx.x + off]);
        }
        __syncthreads();
    }
    if (threadIdx.x < 16) {
        float cnt = fmaxf((float)(n1 - n0), 1.f);
        float sum = rs[threadIdx.x];
        float* row = pooled + (size_t)g * 64;
        row[threadIdx.x] = sum / cnt;        // mean
        row[16 + threadIdx.x] = rmx[threadIdx.x];  // max
        row[32 + threadIdx.x] = rmn[threadIdx.x];  // min
        row[48 + threadIdx.x] = sum;         // sum
    }
}

__global__ void k_fc(const float* __restrict__ pooled, const float* __restrict__ w1,
                     const float* __restrict__ b1, const float* __restrict__ w2,
                     const float* __restrict__ b2, float* __restrict__ fcOut,
                     float* __restrict__ lsmOut, int Gc) {
    int g = blockIdx.x;
    __shared__ float p[64], t16[16], f10[10];
    __shared__ float mred, lred;
    p[threadIdx.x] = pooled[(size_t)g * 64 + threadIdx.x];
    __syncthreads();
    if (threadIdx.x < 16) {
        float s = b1[threadIdx.x];
        for (int k = 0; k < 64; k++) s += p[k] * w1[k * 16 + threadIdx.x];
        t16[threadIdx.x] = tanhf(s);
    }
    __syncthreads();
    if (threadIdx.x < 10) {
        float s = b2[threadIdx.x];
        for (int o = 0; o < 16; o++) s += t16[o] * w2[o * 10 + threadIdx.x];
        f10[threadIdx.x] = s;
        fcOut[(size_t)g * 10 + threadIdx.x] = s;
    }
    __syncthreads();
    if (threadIdx.x == 0) {
        float m = f10[0];
        for (int c = 1; c < 10; c++) m = fmaxf(m, f10[c]);
        float se = 0.f;
        for (int c = 0; c < 10; c++) se += expf(f10[c] - m);
        mred = m;
        lred = logf(se);
    }
    __syncthreads();
    if (threadIdx.x < 10)
        lsmOut[(size_t)g * 10 + threadIdx.x] = f10[threadIdx.x] - mred - lred;
}

// ---------------- host ----------------

extern "C" void kernel_launch(void* const* d_in, const int* in_sizes, int n_in,
                              void* d_out, int out_size, void* d_ws, size_t ws_size,
                              hipStream_t stream) {
    const float* x    = (const float*)d_in[0];
    const float* ea   = (const float*)d_in[1];
    const float* ew1  = (const float*)d_in[2];
    const float* eb1  = (const float*)d_in[3];
    const float* ew2  = (const float*)d_in[4];
    const float* eb2  = (const float*)d_in[5];
    const float* root = (const float*)d_in[6];
    const float* cb   = (const float*)d_in[7];
    const float* gam  = (const float*)d_in[8];
    const float* bet  = (const float*)d_in[9];
    const float* f1w  = (const float*)d_in[10];
    const float* f1b  = (const float*)d_in[11];
    const float* f2w  = (const float*)d_in[12];
    const float* f2b  = (const float*)d_in[13];
    const int* eidx   = (const int*)d_in[14];
    const int* lens   = (const int*)d_in[15];

    int N  = in_sizes[0] / D;
    int E_ = in_sizes[1] / EFD;
    int Gc = in_sizes[15];
    const int* srcIdx = eidx;
    const int* dstIdx = eidx + E_;

    float* outHidden = (float*)d_out;
    float* outPooled = outHidden + (size_t)N * D;
    float* outFc     = outPooled + (size_t)Gc * 4 * D;
    float* outLsm    = outFc + (size_t)Gc * 10;

    char* wsp = (char*)d_ws;
    size_t off = 0;
    auto alloc = [&](size_t bytes) -> void* {
        void* p = wsp + off;
        off = (off + bytes + 255) & ~(size_t)255;
        return p;
    };
    int*   cnt    = (int*)alloc((size_t)N * 4);
    int*   offs   = (int*)alloc((size_t)(N + 1) * 4);
    int*   cursor = (int*)alloc((size_t)N * 4);
    int*   bsum   = (int*)alloc(64 * 4);
    int*   srcS   = (int*)alloc((size_t)E_ * 4);
    int*   eidS   = (int*)alloc((size_t)E_ * 4);
    int*   goffs  = (int*)alloc((size_t)(Gc + 1) * 4);
    float* hE     = (float*)alloc((size_t)E_ * D * 4);
    float* T      = (float*)alloc((size_t)N * TROW * 4);
    float* bufA   = (float*)alloc((size_t)N * D * 4);
    float* tmp    = (float*)alloc((size_t)N * D * 4);
    float* stats  = (float*)alloc(32 * 4);

    int nScan = (N + 1023) / 1024;

    k_zero_i<<<(N + 255) / 256, 256, 0, stream>>>(cnt, N);
    k_hist<<<(E_ + 255) / 256, 256, 0, stream>>>(dstIdx, cnt, E_);
    k_scanA<<<nScan, 1024, 0, stream>>>(cnt, offs, bsum, N);
    k_scanB<<<1, 64, 0, stream>>>(bsum, nScan);
    k_scanC<<<nScan, 1024, 0, stream>>>(offs, cursor, bsum, N, E_);
    k_scatter<<<(E_ + 255) / 256, 256, 0, stream>>>(srcIdx, dstIdx, cursor, srcS, eidS, E_);
    k_he<<<(E_ * D + 255) / 256, 256, 0, stream>>>(ea, ew1, eb1, eidS, hE, E_);

    for (int l = 0; l < 3; l++) {
        const float* hin = (l == 0) ? x : bufA;
        float* bnout = (l == 2) ? outHidden : bufA;
        k_T<<<N, TROW, 0, stream>>>(hin, ew2, eb2, T, stats, N);
        k_conv<<<(N + 15) / 16, 256, 0, stream>>>(hin, T, hE, srcS, offs,
                                                  root + (size_t)l * 256, cb + (size_t)l * 16,
                                                  tmp, stats, N);
        k_bn<<<((size_t)N * D + 255) / 256, 256, 0, stream>>>(tmp, stats,
                                                              gam + (size_t)l * 16,
                                                              bet + (size_t)l * 16, bnout, N);
    }

    k_gscan<<<1, 512, 0, stream>>>(lens, goffs, Gc);
    k_pool<<<Gc, 64, 0, stream>>>(outHidden, goffs, outPooled, Gc);
    k_fc<<<Gc, 64, 0, stream>>>(outPooled, f1w, f1b, f2w, f2b, outFc, outLsm, Gc);
}

// Round 2
// 577.687 us; speedup vs baseline: 1.1018x; 1.1018x over previous
//
#include <hip/hip_runtime.h>

#define D 16
#define EFD 8
#define TROW 272   // 256 T values (j*16+o) + 16 bias-projection values B[o]

// ---------------- preprocessing: counting sorts of edges by src and by dst ----------------

__global__ void k_zero_i(int* p, int n) {
    int i = blockIdx.x * 256 + threadIdx.x;
    if (i < n) p[i] = 0;
}

__global__ void k_hist2(const int* __restrict__ src, const int* __restrict__ dst,
                        int* __restrict__ cntS, int* __restrict__ cntD, int E_) {
    int e = blockIdx.x * 256 + threadIdx.x;
    if (e < E_) {
        atomicAdd(&cntS[src[e]], 1);
        atomicAdd(&cntD[dst[e]], 1);
    }
}

__global__ void k_scanA(const int* __restrict__ cnt, int* __restrict__ offs,
                        int* __restrict__ bsum, int n) {
    __shared__ int s[1024];
    int i = blockIdx.x * 1024 + threadIdx.x;
    int v = (i < n) ? cnt[i] : 0;
    s[threadIdx.x] = v;
    __syncthreads();
    for (int d = 1; d < 1024; d <<= 1) {
        int t = (threadIdx.x >= d) ? s[threadIdx.x - d] : 0;
        __syncthreads();
        s[threadIdx.x] += t;
        __syncthreads();
    }
    int incl = s[threadIdx.x];
    if (i < n) offs[i] = incl - v;          // exclusive within chunk
    if (threadIdx.x == 1023) bsum[blockIdx.x] = incl;
}

__global__ void k_scanB(int* bsum, int nb) {
    __shared__ int s[64];
    int v = (threadIdx.x < nb) ? bsum[threadIdx.x] : 0;
    s[threadIdx.x] = v;
    __syncthreads();
    for (int d = 1; d < 64; d <<= 1) {
        int t = (threadIdx.x >= d) ? s[threadIdx.x - d] : 0;
        __syncthreads();
        s[threadIdx.x] += t;
        __syncthreads();
    }
    if (threadIdx.x < nb) bsum[threadIdx.x] = s[threadIdx.x] - v;  // exclusive
}

__global__ void k_scanC(int* __restrict__ offs, int* __restrict__ cursor,
                        const int* __restrict__ bsum, int n, int total) {
    int i = blockIdx.x * 1024 + threadIdx.x;
    if (i < n) {
        int v = offs[i] + bsum[blockIdx.x];
        offs[i] = v;
        cursor[i] = v;
    } else if (i == n) {
        offs[n] = total;
    }
}

__global__ void k_scatterS(const int* __restrict__ src, int* __restrict__ cursorS,
                           int* __restrict__ eidSrc, int* __restrict__ invSrc, int E_) {
    int e = blockIdx.x * 256 + threadIdx.x;
    if (e < E_) {
        int p = atomicAdd(&cursorS[src[e]], 1);
        eidSrc[p] = e;
        invSrc[e] = p;
    }
}

__global__ void k_scatterD(const int* __restrict__ dst, int* __restrict__ cursorD,
                           int* __restrict__ eidD, int E_) {
    int e = blockIdx.x * 256 + threadIdx.x;
    if (e < E_) {
        int p = atomicAdd(&cursorD[dst[e]], 1);
        eidD[p] = e;
    }
}

// perm: dst-sorted position -> src-sorted position
__global__ void k_perm(const int* __restrict__ eidD, const int* __restrict__ invSrc,
                       int* __restrict__ perm, int E_) {
    int p = blockIdx.x * 256 + threadIdx.x;
    if (p < E_) perm[p] = invSrc[eidD[p]];
}

// ---------------- edge MLP layer 1 (shared across layers), stored src-sorted ----------------

__global__ void k_he(const float* __restrict__ ea, const float* __restrict__ w1,
                     const float* __restrict__ b1, const int* __restrict__ eidSrc,
                     float* __restrict__ hE, int E_) {
    __shared__ float w1s[EFD * D];
    if (threadIdx.x < EFD * D) w1s[threadIdx.x] = w1[threadIdx.x];
    __syncthreads();
    int t = blockIdx.x * 256 + threadIdx.x;
    int p = t >> 4, o = t & 15;
    if (p < E_) {
        int e = eidSrc[p];
        const float4* a4 = (const float4*)(ea + (size_t)e * EFD);
        float4 x0 = a4[0], x1 = a4[1];
        float s = b1[o];
        s += x0.x * w1s[0 * D + o] + x0.y * w1s[1 * D + o] +
             x0.z * w1s[2 * D + o] + x0.w * w1s[3 * D + o] +
             x1.x * w1s[4 * D + o] + x1.y * w1s[5 * D + o] +
             x1.z * w1s[6 * D + o] + x1.w * w1s[7 * D + o];
        hE[(size_t)p * D + o] = tanhf(s);
    }
}

// ---------------- per-layer: T[n,j,o] = sum_i h[n,i]*w2[j,i*16+o] ; 32 nodes/block, w2 in LDS ----------------

#define TNB 32
#define W2STRIDE 272  // 272 mod 32 == 16 -> 2-way LDS bank aliasing (free)

__global__ void k_T(const float* __restrict__ h, const float* __restrict__ w2,
                    const float* __restrict__ b2, float* __restrict__ T,
                    float* __restrict__ stats, int n) {
    __shared__ float w2s[D * W2STRIDE];   // [j][i*16+o], padded stride
    __shared__ float b2s[256];
    __shared__ float hs[TNB * D];
    if (blockIdx.x == 0 && threadIdx.x < 32) stats[threadIdx.x] = 0.f;  // zero BN stats
    // stage w2 (4096 floats) and b2 (256)
    for (int c = threadIdx.x; c < D * 256; c += 256) {
        int j = c >> 8, r = c & 255;
        w2s[j * W2STRIDE + r] = w2[c];
    }
    b2s[threadIdx.x] = b2[threadIdx.x];
    int base = blockIdx.x * TNB;
    // stage h rows (TNB*16 = 512 floats)
    for (int c = threadIdx.x; c < TNB * D; c += 256) {
        int node = base + (c >> 4);
        hs[c] = (node < n) ? h[(size_t)node * D + (c & 15)] : 0.f;
    }
    __syncthreads();
    int j = threadIdx.x >> 4, o = threadIdx.x & 15;
    for (int nb = 0; nb < TNB; nb++) {
        int node = base + nb;
        if (node >= n) break;
        float s = 0.f;
#pragma unroll
        for (int i = 0; i < D; i++)
            s += hs[nb * D + i] * w2s[j * W2STRIDE + i * D + o];
        T[(size_t)node * TROW + threadIdx.x] = s;
    }
    // bias projection: 256 threads cover 16 nodes at a time
    int nb2 = threadIdx.x >> 4;
    for (int g = 0; g < TNB / 16; g++) {
        int node = base + g * 16 + nb2;
        if (node < n) {
            float s = 0.f;
#pragma unroll
            for (int i = 0; i < D; i++)
                s += hs[(g * 16 + nb2) * D + i] * b2s[i * D + o];
            T[(size_t)node * TROW + 256 + o] = s;
        }
    }
}

// ---------------- per-layer: per-edge messages, src-sorted (T row register-resident) ----------------

__global__ void k_msg(const float* __restrict__ T, const float* __restrict__ hE,
                      const int* __restrict__ offsS, float* __restrict__ msg, int n) {
    int slot = threadIdx.x >> 4, o = threadIdx.x & 15;
    int s = blockIdx.x * 16 + slot;
    if (s >= n) return;
    const float* Trow = T + (size_t)s * TROW;
    float tr[D];
#pragma unroll
    for (int j = 0; j < D; j++) tr[j] = Trow[j * D + o];
    float tb = Trow[256 + o];
    int p0 = offsS[s], p1 = offsS[s + 1];
    for (int p = p0; p < p1; p++) {
        const float4* he4 = (const float4*)(hE + (size_t)p * D);
        float4 a0 = he4[0], a1 = he4[1], a2 = he4[2], a3 = he4[3];
        float a = tb
            + a0.x * tr[0] + a0.y * tr[1] + a0.z * tr[2] + a0.w * tr[3]
            + a1.x * tr[4] + a1.y * tr[5] + a1.z * tr[6] + a1.w * tr[7]
            + a2.x * tr[8] + a2.y * tr[9] + a2.z * tr[10] + a2.w * tr[11]
            + a3.x * tr[12] + a3.y * tr[13] + a3.z * tr[14] + a3.w * tr[15];
        msg[(size_t)p * D + o] = a;
    }
}

// ---------------- per-layer: dst aggregation + root + bias + BN partial stats ----------------

__global__ void k_agg(const float* __restrict__ h, const float* __restrict__ msg,
                      const int* __restrict__ perm, const int* __restrict__ offsD,
                      const float* __restrict__ root_l, const float* __restrict__ cbias,
                      float* __restrict__ hpre, float* __restrict__ stats, int n) {
    __shared__ float rootS[D * D];
    __shared__ float red[256], red2[256];
    if (threadIdx.x < D * D) rootS[threadIdx.x] = root_l[threadIdx.x];
    __syncthreads();
    int slot = threadIdx.x >> 4, o = threadIdx.x & 15;
    int node = blockIdx.x * 16 + slot;
    float acc = 0.f;
    if (node < n) {
        int p0 = offsD[node], p1 = offsD[node + 1];
        float sum = 0.f;
        for (int p = p0; p < p1; p++) {
            int q = perm[p];
            sum += msg[(size_t)q * D + o];
        }
        float deg = (float)((p1 - p0) > 1 ? (p1 - p0) : 1);
        float r = cbias[o];
        const float* hr = h + (size_t)node * D;
#pragma unroll
        for (int i = 0; i < D; i++) r += hr[i] * rootS[i * D + o];
        acc = sum / deg + r;
        hpre[(size_t)node * D + o] = acc;
    }
    red[threadIdx.x] = acc;
    red2[threadIdx.x] = acc * acc;
    __syncthreads();
    for (int off = 128; off >= 16; off >>= 1) {
        if (threadIdx.x < off) {
            red[threadIdx.x] += red[threadIdx.x + off];
            red2[threadIdx.x] += red2[threadIdx.x + off];
        }
        __syncthreads();
    }
    if (threadIdx.x < 16) {
        atomicAdd(&stats[threadIdx.x], red[threadIdx.x]);
        atomicAdd(&stats[16 + threadIdx.x], red2[threadIdx.x]);
    }
}

// ---------------- per-layer: BatchNorm apply + tanh ----------------

__global__ void k_bn(const float* __restrict__ hpre, const float* __restrict__ stats,
                     const float* __restrict__ gamma, const float* __restrict__ beta,
                     float* __restrict__ out, int n) {
    int i = blockIdx.x * 256 + threadIdx.x;
    if (i < n * D) {
        int o = i & 15;
        float fn = (float)n;
        float mu = stats[o] / fn;
        float var = stats[16 + o] / fn - mu * mu;
        float x = hpre[i];
        float y = (x - mu) * rsqrtf(var + 1e-5f) * gamma[o] + beta[o];
        out[i] = tanhf(y);
    }
}

// ---------------- readout ----------------

__global__ void k_gscan(const int* __restrict__ lengths, int* __restrict__ goffs, int Gc) {
    __shared__ int s[512];
    int v = (threadIdx.x < Gc) ? lengths[threadIdx.x] : 0;
    s[threadIdx.x] = v;
    __syncthreads();
    for (int d = 1; d < 512; d <<= 1) {
        int t = (threadIdx.x >= d) ? s[threadIdx.x - d] : 0;
        __syncthreads();
        s[threadIdx.x] += t;
        __syncthreads();
    }
    if (threadIdx.x < Gc) goffs[threadIdx.x] = s[threadIdx.x] - v;
    if (threadIdx.x == Gc - 1) goffs[Gc] = s[threadIdx.x];
}

__global__ void k_pool(const float* __restrict__ hidden, const int* __restrict__ goffs,
                       float* __restrict__ pooled, int Gc) {
    int g = blockIdx.x;
    int slot = threadIdx.x >> 4, o = threadIdx.x & 15;  // 4 slots x 16 ch
    int n0 = goffs[g], n1 = goffs[g + 1];
    float s = 0.f, mx = -3.402823466e38f, mn = 3.402823466e38f;
    for (int nd = n0 + slot; nd < n1; nd += 4) {
        float v = hidden[(size_t)nd * D + o];
        s += v;
        mx = fmaxf(mx, v);
        mn = fminf(mn, v);
    }
    __shared__ float rs[64], rmx[64], rmn[64];
    rs[threadIdx.x] = s; rmx[threadIdx.x] = mx; rmn[threadIdx.x] = mn;
    __syncthreads();
    for (int off = 32; off >= 16; off >>= 1) {
        if (threadIdx.x < off) {
            rs[threadIdx.x] += rs[threadIdx.x + off];
            rmx[threadIdx.x] = fmaxf(rmx[threadIdx.x], rmx[threadIdx.x + off]);
            rmn[threadIdx.x] = fminf(rmn[threadIdx.x], rmn[threadIdx.x + off]);
        }
        __syncthreads();
    }
    if (threadIdx.x < 16) {
        float cnt = fmaxf((float)(n1 - n0), 1.f);
        float sum = rs[threadIdx.x];
        float* row = pooled + (size_t)g * 64;
        row[threadIdx.x] = sum / cnt;              // mean
        row[16 + threadIdx.x] = rmx[threadIdx.x];  // max
        row[32 + threadIdx.x] = rmn[threadIdx.x];  // min
        row[48 + threadIdx.x] = sum;               // sum
    }
}

__global__ void k_fc(const float* __restrict__ pooled, const float* __restrict__ w1,
                     const float* __restrict__ b1, const float* __restrict__ w2,
                     const float* __restrict__ b2, float* __restrict__ fcOut,
                     float* __restrict__ lsmOut, int Gc) {
    int g = blockIdx.x;
    __shared__ float p[64], t16[16], f10[10];
    __shared__ float mred, lred;
    p[threadIdx.x] = pooled[(size_t)g * 64 + threadIdx.x];
    __syncthreads();
    if (threadIdx.x < 16) {
        float s = b1[threadIdx.x];
        for (int k = 0; k < 64; k++) s += p[k] * w1[k * 16 + threadIdx.x];
        t16[threadIdx.x] = tanhf(s);
    }
    __syncthreads();
    if (threadIdx.x < 10) {
        float s = b2[threadIdx.x];
        for (int o = 0; o < 16; o++) s += t16[o] * w2[o * 10 + threadIdx.x];
        f10[threadIdx.x] = s;
        fcOut[(size_t)g * 10 + threadIdx.x] = s;
    }
    __syncthreads();
    if (threadIdx.x == 0) {
        float m = f10[0];
        for (int c = 1; c < 10; c++) m = fmaxf(m, f10[c]);
        float se = 0.f;
        for (int c = 0; c < 10; c++) se += expf(f10[c] - m);
        mred = m;
        lred = logf(se);
    }
    __syncthreads();
    if (threadIdx.x < 10)
        lsmOut[(size_t)g * 10 + threadIdx.x] = f10[threadIdx.x] - mred - lred;
}

// ---------------- host ----------------

extern "C" void kernel_launch(void* const* d_in, const int* in_sizes, int n_in,
                              void* d_out, int out_size, void* d_ws, size_t ws_size,
                              hipStream_t stream) {
    const float* x    = (const float*)d_in[0];
    const float* ea   = (const float*)d_in[1];
    const float* ew1  = (const float*)d_in[2];
    const float* eb1  = (const float*)d_in[3];
    const float* ew2  = (const float*)d_in[4];
    const float* eb2  = (const float*)d_in[5];
    const float* root = (const float*)d_in[6];
    const float* cb   = (const float*)d_in[7];
    const float* gam  = (const float*)d_in[8];
    const float* bet  = (const float*)d_in[9];
    const float* f1w  = (const float*)d_in[10];
    const float* f1b  = (const float*)d_in[11];
    const float* f2w  = (const float*)d_in[12];
    const float* f2b  = (const float*)d_in[13];
    const int* eidx   = (const int*)d_in[14];
    const int* lens   = (const int*)d_in[15];

    int N  = in_sizes[0] / D;
    int E_ = in_sizes[1] / EFD;
    int Gc = in_sizes[15];
    const int* srcIdx = eidx;
    const int* dstIdx = eidx + E_;

    float* outHidden = (float*)d_out;
    float* outPooled = outHidden + (size_t)N * D;
    float* outFc     = outPooled + (size_t)Gc * 4 * D;
    float* outLsm    = outFc + (size_t)Gc * 10;

    char* wsp = (char*)d_ws;
    size_t off = 0;
    auto alloc = [&](size_t bytes) -> void* {
        void* p = wsp + off;
        off = (off + bytes + 255) & ~(size_t)255;
        return p;
    };
    int*   cntS    = (int*)alloc((size_t)2 * N * 4);   // cntS | cntD contiguous
    int*   cntD    = cntS + N;
    int*   offsS   = (int*)alloc((size_t)(N + 1) * 4);
    int*   offsD   = (int*)alloc((size_t)(N + 1) * 4);
    int*   cursorS = (int*)alloc((size_t)N * 4);
    int*   cursorD = (int*)alloc((size_t)N * 4);
    int*   bsumS   = (int*)alloc(64 * 4);
    int*   bsumD   = (int*)alloc(64 * 4);
    int*   eidSrc  = (int*)alloc((size_t)E_ * 4);
    int*   invSrc  = (int*)alloc((size_t)E_ * 4);
    int*   eidD    = (int*)alloc((size_t)E_ * 4);
    int*   perm    = (int*)alloc((size_t)E_ * 4);
    int*   goffs   = (int*)alloc((size_t)(Gc + 1) * 4);
    float* hE      = (float*)alloc((size_t)E_ * D * 4);
    float* T       = (float*)alloc((size_t)N * TROW * 4);
    float* msg     = (float*)alloc((size_t)E_ * D * 4);
    float* bufA    = (float*)alloc((size_t)N * D * 4);
    float* tmp     = (float*)alloc((size_t)N * D * 4);
    float* stats   = (float*)alloc(32 * 4);

    int nScan = (N + 1023) / 1024;

    k_zero_i<<<(2 * N + 255) / 256, 256, 0, stream>>>(cntS, 2 * N);
    k_hist2<<<(E_ + 255) / 256, 256, 0, stream>>>(srcIdx, dstIdx, cntS, cntD, E_);
    k_scanA<<<nScan, 1024, 0, stream>>>(cntS, offsS, bsumS, N);
    k_scanB<<<1, 64, 0, stream>>>(bsumS, nScan);
    k_scanC<<<nScan, 1024, 0, stream>>>(offsS, cursorS, bsumS, N, E_);
    k_scanA<<<nScan, 1024, 0, stream>>>(cntD, offsD, bsumD, N);
    k_scanB<<<1, 64, 0, stream>>>(bsumD, nScan);
    k_scanC<<<nScan, 1024, 0, stream>>>(offsD, cursorD, bsumD, N, E_);
    k_scatterS<<<(E_ + 255) / 256, 256, 0, stream>>>(srcIdx, cursorS, eidSrc, invSrc, E_);
    k_scatterD<<<(E_ + 255) / 256, 256, 0, stream>>>(dstIdx, cursorD, eidD, E_);
    k_perm<<<(E_ + 255) / 256, 256, 0, stream>>>(eidD, invSrc, perm, E_);
    k_he<<<(E_ * D + 255) / 256, 256, 0, stream>>>(ea, ew1, eb1, eidSrc, hE, E_);

    for (int l = 0; l < 3; l++) {
        const float* hin = (l == 0) ? x : bufA;
        float* bnout = (l == 2) ? outHidden : bufA;
        k_T<<<(N + TNB - 1) / TNB, 256, 0, stream>>>(hin, ew2, eb2, T, stats, N);
        k_msg<<<(N + 15) / 16, 256, 0, stream>>>(T, hE, offsS, msg, N);
        k_agg<<<(N + 15) / 16, 256, 0, stream>>>(hin, msg, perm, offsD,
                                                 root + (size_t)l * 256, cb + (size_t)l * 16,
                                                 tmp, stats, N);
        k_bn<<<((size_t)N * D + 255) / 256, 256, 0, stream>>>(tmp, stats,
                                                              gam + (size_t)l * 16,
                                                              bet + (size_t)l * 16, bnout, N);
    }

    k_gscan<<<1, 512, 0, stream>>>(lens, goffs, Gc);
    k_pool<<<Gc, 64, 0, stream>>>(outHidden, goffs, outPooled, Gc);
    k_fc<<<Gc, 64, 0, stream>>>(outPooled, f1w, f1b, f2w, f2b, outFc, outLsm, Gc);
}

// Round 3
// 575.349 us; speedup vs baseline: 1.1063x; 1.0041x over previous
//
#include <hip/hip_runtime.h>

#define D 16
#define EFD 8
#define TROW 272   // 256 T values (j*16+o) + 16 bias-projection values B[o]

// ---------------- preprocessing: counting sorts of edges by src and by dst ----------------

__global__ void k_zero_i(int* p, int n) {
    int i = blockIdx.x * 256 + threadIdx.x;
    if (i < n) p[i] = 0;
}

__global__ void k_hist2(const int* __restrict__ src, const int* __restrict__ dst,
                        int* __restrict__ cntS, int* __restrict__ cntD, int E_) {
    int e = blockIdx.x * 256 + threadIdx.x;
    if (e < E_) {
        atomicAdd(&cntS[src[e]], 1);
        atomicAdd(&cntD[dst[e]], 1);
    }
}

__global__ void k_scanA(const int* __restrict__ cnt, int* __restrict__ offs,
                        int* __restrict__ bsum, int n) {
    __shared__ int s[1024];
    int i = blockIdx.x * 1024 + threadIdx.x;
    int v = (i < n) ? cnt[i] : 0;
    s[threadIdx.x] = v;
    __syncthreads();
    for (int d = 1; d < 1024; d <<= 1) {
        int t = (threadIdx.x >= d) ? s[threadIdx.x - d] : 0;
        __syncthreads();
        s[threadIdx.x] += t;
        __syncthreads();
    }
    int incl = s[threadIdx.x];
    if (i < n) offs[i] = incl - v;          // exclusive within chunk
    if (threadIdx.x == 1023) bsum[blockIdx.x] = incl;
}

__global__ void k_scanB(int* bsum, int nb) {
    __shared__ int s[64];
    int v = (threadIdx.x < nb) ? bsum[threadIdx.x] : 0;
    s[threadIdx.x] = v;
    __syncthreads();
    for (int d = 1; d < 64; d <<= 1) {
        int t = (threadIdx.x >= d) ? s[threadIdx.x - d] : 0;
        __syncthreads();
        s[threadIdx.x] += t;
        __syncthreads();
    }
    if (threadIdx.x < nb) bsum[threadIdx.x] = s[threadIdx.x] - v;  // exclusive
}

__global__ void k_scanC(int* __restrict__ offs, int* __restrict__ cursor,
                        const int* __restrict__ bsum, int n, int total) {
    int i = blockIdx.x * 1024 + threadIdx.x;
    if (i < n) {
        int v = offs[i] + bsum[blockIdx.x];
        offs[i] = v;
        cursor[i] = v;
    } else if (i == n) {
        offs[n] = total;
    }
}

__global__ void k_scatterS(const int* __restrict__ src, int* __restrict__ cursorS,
                           int* __restrict__ eidSrc, int* __restrict__ invSrc, int E_) {
    int e = blockIdx.x * 256 + threadIdx.x;
    if (e < E_) {
        int p = atomicAdd(&cursorS[src[e]], 1);
        eidSrc[p] = e;
        invSrc[e] = p;
    }
}

// dst counting-sort position, recorded as permInv: src-sorted pos -> dst-sorted pos
__global__ void k_scatterD(const int* __restrict__ dst, const int* __restrict__ invSrc,
                           int* __restrict__ cursorD, int* __restrict__ permInv, int E_) {
    int e = blockIdx.x * 256 + threadIdx.x;
    if (e < E_) {
        int p = atomicAdd(&cursorD[dst[e]], 1);
        permInv[invSrc[e]] = p;
    }
}

// ---------------- edge MLP layer 1 (shared across layers), stored src-sorted ----------------

__global__ void k_he(const float* __restrict__ ea, const float* __restrict__ w1,
                     const float* __restrict__ b1, const int* __restrict__ eidSrc,
                     float* __restrict__ hE, int E_) {
    __shared__ float w1s[EFD * D];
    if (threadIdx.x < EFD * D) w1s[threadIdx.x] = w1[threadIdx.x];
    __syncthreads();
    int t = blockIdx.x * 256 + threadIdx.x;
    int p = t >> 4, o = t & 15;
    if (p < E_) {
        int e = eidSrc[p];
        const float4* a4 = (const float4*)(ea + (size_t)e * EFD);
        float4 x0 = a4[0], x1 = a4[1];
        float s = b1[o];
        s += x0.x * w1s[0 * D + o] + x0.y * w1s[1 * D + o] +
             x0.z * w1s[2 * D + o] + x0.w * w1s[3 * D + o] +
             x1.x * w1s[4 * D + o] + x1.y * w1s[5 * D + o] +
             x1.z * w1s[6 * D + o] + x1.w * w1s[7 * D + o];
        hE[(size_t)p * D + o] = tanhf(s);
    }
}

// ---------------- per-layer: T[n,j,o] = sum_i h[n,i]*w2[j,i*16+o] ; 32 nodes/block, w2 in LDS ----------------

#define TNB 32
#define W2STRIDE 272  // 272 mod 32 == 16 -> 2-way LDS bank aliasing (free)

__global__ void k_T(const float* __restrict__ h, const float* __restrict__ w2,
                    const float* __restrict__ b2, float* __restrict__ T,
                    float* __restrict__ stats, int n) {
    __shared__ float w2s[D * W2STRIDE];   // [j][i*16+o], padded stride
    __shared__ float b2s[256];
    __shared__ float hs[TNB * D];
    if (blockIdx.x == 0 && threadIdx.x < 32) stats[threadIdx.x] = 0.f;  // zero BN stats
    for (int c = threadIdx.x; c < D * 256; c += 256) {
        int j = c >> 8, r = c & 255;
        w2s[j * W2STRIDE + r] = w2[c];
    }
    b2s[threadIdx.x] = b2[threadIdx.x];
    int base = blockIdx.x * TNB;
    for (int c = threadIdx.x; c < TNB * D; c += 256) {
        int node = base + (c >> 4);
        hs[c] = (node < n) ? h[(size_t)node * D + (c & 15)] : 0.f;
    }
    __syncthreads();
    int j = threadIdx.x >> 4, o = threadIdx.x & 15;
    for (int nb = 0; nb < TNB; nb++) {
        int node = base + nb;
        if (node >= n) break;
        float s = 0.f;
#pragma unroll
        for (int i = 0; i < D; i++)
            s += hs[nb * D + i] * w2s[j * W2STRIDE + i * D + o];
        T[(size_t)node * TROW + threadIdx.x] = s;
    }
    int nb2 = threadIdx.x >> 4;
    for (int g = 0; g < TNB / 16; g++) {
        int node = base + g * 16 + nb2;
        if (node < n) {
            float s = 0.f;
#pragma unroll
            for (int i = 0; i < D; i++)
                s += hs[(g * 16 + nb2) * D + i] * b2s[i * D + o];
            T[(size_t)node * TROW + 256 + o] = s;
        }
    }
}

// ---------------- per-layer: per-edge messages, src-ordered compute, dst-ordered scatter write ----------------

__global__ void k_msg(const float* __restrict__ T, const float* __restrict__ hE,
                      const int* __restrict__ offsS, const int* __restrict__ permInv,
                      float* __restrict__ msg, int n) {
    int slot = threadIdx.x >> 4, o = threadIdx.x & 15;
    int s = blockIdx.x * 16 + slot;
    if (s >= n) return;
    const float* Trow = T + (size_t)s * TROW;
    float tr[D];
#pragma unroll
    for (int j = 0; j < D; j++) tr[j] = Trow[j * D + o];
    float tb = Trow[256 + o];
    int p0 = offsS[s], p1 = offsS[s + 1];
    for (int p = p0; p < p1; p++) {
        const float4* he4 = (const float4*)(hE + (size_t)p * D);
        float4 a0 = he4[0], a1 = he4[1], a2 = he4[2], a3 = he4[3];
        float a = tb
            + a0.x * tr[0] + a0.y * tr[1] + a0.z * tr[2] + a0.w * tr[3]
            + a1.x * tr[4] + a1.y * tr[5] + a1.z * tr[6] + a1.w * tr[7]
            + a2.x * tr[8] + a2.y * tr[9] + a2.z * tr[10] + a2.w * tr[11]
            + a3.x * tr[12] + a3.y * tr[13] + a3.z * tr[14] + a3.w * tr[15];
        int q = permInv[p];                       // dst-sorted slot
        msg[(size_t)q * D + o] = a;               // scattered 64B-row store (fire-and-forget)
    }
}

// ---------------- per-layer: dst aggregation (sequential msg read) + root + bias + BN stats ----------------

__global__ void k_agg(const float* __restrict__ h, const float* __restrict__ msg,
                      const int* __restrict__ offsD, const float* __restrict__ root_l,
                      const float* __restrict__ cbias, float* __restrict__ hpre,
                      float* __restrict__ stats, int n) {
    __shared__ float rootS[D * D];
    __shared__ float red[256], red2[256];
    if (threadIdx.x < D * D) rootS[threadIdx.x] = root_l[threadIdx.x];
    __syncthreads();
    int slot = threadIdx.x >> 4, o = threadIdx.x & 15;
    int node = blockIdx.x * 16 + slot;
    float acc = 0.f;
    if (node < n) {
        int p0 = offsD[node], p1 = offsD[node + 1];
        float sum = 0.f;
        for (int p = p0; p < p1; p++)
            sum += msg[(size_t)p * D + o];        // contiguous rows
        float deg = (float)((p1 - p0) > 1 ? (p1 - p0) : 1);
        float r = cbias[o];
        const float* hr = h + (size_t)node * D;
#pragma unroll
        for (int i = 0; i < D; i++) r += hr[i] * rootS[i * D + o];
        acc = sum / deg + r;
        hpre[(size_t)node * D + o] = acc;
    }
    red[threadIdx.x] = acc;
    red2[threadIdx.x] = acc * acc;
    __syncthreads();
    for (int off = 128; off >= 16; off >>= 1) {
        if (threadIdx.x < off) {
            red[threadIdx.x] += red[threadIdx.x + off];
            red2[threadIdx.x] += red2[threadIdx.x + off];
        }
        __syncthreads();
    }
    if (threadIdx.x < 16) {
        atomicAdd(&stats[threadIdx.x], red[threadIdx.x]);
        atomicAdd(&stats[16 + threadIdx.x], red2[threadIdx.x]);
    }
}

// ---------------- per-layer: BatchNorm apply + tanh ----------------

__global__ void k_bn(const float* __restrict__ hpre, const float* __restrict__ stats,
                     const float* __restrict__ gamma, const float* __restrict__ beta,
                     float* __restrict__ out, int n) {
    int i = blockIdx.x * 256 + threadIdx.x;
    if (i < n * D) {
        int o = i & 15;
        float fn = (float)n;
        float mu = stats[o] / fn;
        float var = stats[16 + o] / fn - mu * mu;
        float x = hpre[i];
        float y = (x - mu) * rsqrtf(var + 1e-5f) * gamma[o] + beta[o];
        out[i] = tanhf(y);
    }
}

// ---------------- readout ----------------

__global__ void k_gscan(const int* __restrict__ lengths, int* __restrict__ goffs, int Gc) {
    __shared__ int s[512];
    int v = (threadIdx.x < Gc) ? lengths[threadIdx.x] : 0;
    s[threadIdx.x] = v;
    __syncthreads();
    for (int d = 1; d < 512; d <<= 1) {
        int t = (threadIdx.x >= d) ? s[threadIdx.x - d] : 0;
        __syncthreads();
        s[threadIdx.x] += t;
        __syncthreads();
    }
    if (threadIdx.x < Gc) goffs[threadIdx.x] = s[threadIdx.x] - v;
    if (threadIdx.x == Gc - 1) goffs[Gc] = s[threadIdx.x];
}

__global__ void k_pool(const float* __restrict__ hidden, const int* __restrict__ goffs,
                       float* __restrict__ pooled, int Gc) {
    int g = blockIdx.x;
    int slot = threadIdx.x >> 4, o = threadIdx.x & 15;  // 4 slots x 16 ch
    int n0 = goffs[g], n1 = goffs[g + 1];
    float s = 0.f, mx = -3.402823466e38f, mn = 3.402823466e38f;
    for (int nd = n0 + slot; nd < n1; nd += 4) {
        float v = hidden[(size_t)nd * D + o];
        s += v;
        mx = fmaxf(mx, v);
        mn = fminf(mn, v);
    }
    __shared__ float rs[64], rmx[64], rmn[64];
    rs[threadIdx.x] = s; rmx[threadIdx.x] = mx; rmn[threadIdx.x] = mn;
    __syncthreads();
    for (int off = 32; off >= 16; off >>= 1) {
        if (threadIdx.x < off) {
            rs[threadIdx.x] += rs[threadIdx.x + off];
            rmx[threadIdx.x] = fmaxf(rmx[threadIdx.x], rmx[threadIdx.x + off]);
            rmn[threadIdx.x] = fminf(rmn[threadIdx.x], rmn[threadIdx.x + off]);
        }
        __syncthreads();
    }
    if (threadIdx.x < 16) {
        float cnt = fmaxf((float)(n1 - n0), 1.f);
        float sum = rs[threadIdx.x];
        float* row = pooled + (size_t)g * 64;
        row[threadIdx.x] = sum / cnt;              // mean
        row[16 + threadIdx.x] = rmx[threadIdx.x];  // max
        row[32 + threadIdx.x] = rmn[threadIdx.x];  // min
        row[48 + threadIdx.x] = sum;               // sum
    }
}

__global__ void k_fc(const float* __restrict__ pooled, const float* __restrict__ w1,
                     const float* __restrict__ b1, const float* __restrict__ w2,
                     const float* __restrict__ b2, float* __restrict__ fcOut,
                     float* __restrict__ lsmOut, int Gc) {
    int g = blockIdx.x;
    __shared__ float p[64], t16[16], f10[10];
    __shared__ float mred, lred;
    p[threadIdx.x] = pooled[(size_t)g * 64 + threadIdx.x];
    __syncthreads();
    if (threadIdx.x < 16) {
        float s = b1[threadIdx.x];
        for (int k = 0; k < 64; k++) s += p[k] * w1[k * 16 + threadIdx.x];
        t16[threadIdx.x] = tanhf(s);
    }
    __syncthreads();
    if (threadIdx.x < 10) {
        float s = b2[threadIdx.x];
        for (int o = 0; o < 16; o++) s += t16[o] * w2[o * 10 + threadIdx.x];
        f10[threadIdx.x] = s;
        fcOut[(size_t)g * 10 + threadIdx.x] = s;
    }
    __syncthreads();
    if (threadIdx.x == 0) {
        float m = f10[0];
        for (int c = 1; c < 10; c++) m = fmaxf(m, f10[c]);
        float se = 0.f;
        for (int c = 0; c < 10; c++) se += expf(f10[c] - m);
        mred = m;
        lred = logf(se);
    }
    __syncthreads();
    if (threadIdx.x < 10)
        lsmOut[(size_t)g * 10 + threadIdx.x] = f10[threadIdx.x] - mred - lred;
}

// ---------------- host ----------------

extern "C" void kernel_launch(void* const* d_in, const int* in_sizes, int n_in,
                              void* d_out, int out_size, void* d_ws, size_t ws_size,
                              hipStream_t stream) {
    const float* x    = (const float*)d_in[0];
    const float* ea   = (const float*)d_in[1];
    const float* ew1  = (const float*)d_in[2];
    const float* eb1  = (const float*)d_in[3];
    const float* ew2  = (const float*)d_in[4];
    const float* eb2  = (const float*)d_in[5];
    const float* root = (const float*)d_in[6];
    const float* cb   = (const float*)d_in[7];
    const float* gam  = (const float*)d_in[8];
    const float* bet  = (const float*)d_in[9];
    const float* f1w  = (const float*)d_in[10];
    const float* f1b  = (const float*)d_in[11];
    const float* f2w  = (const float*)d_in[12];
    const float* f2b  = (const float*)d_in[13];
    const int* eidx   = (const int*)d_in[14];
    const int* lens   = (const int*)d_in[15];

    int N  = in_sizes[0] / D;
    int E_ = in_sizes[1] / EFD;
    int Gc = in_sizes[15];
    const int* srcIdx = eidx;
    const int* dstIdx = eidx + E_;

    float* outHidden = (float*)d_out;
    float* outPooled = outHidden + (size_t)N * D;
    float* outFc     = outPooled + (size_t)Gc * 4 * D;
    float* outLsm    = outFc + (size_t)Gc * 10;

    char* wsp = (char*)d_ws;
    size_t off = 0;
    auto alloc = [&](size_t bytes) -> void* {
        void* p = wsp + off;
        off = (off + bytes + 255) & ~(size_t)255;
        return p;
    };
    int*   cntS    = (int*)alloc((size_t)2 * N * 4);   // cntS | cntD contiguous
    int*   cntD    = cntS + N;
    int*   offsS   = (int*)alloc((size_t)(N + 1) * 4);
    int*   offsD   = (int*)alloc((size_t)(N + 1) * 4);
    int*   cursorS = (int*)alloc((size_t)N * 4);
    int*   cursorD = (int*)alloc((size_t)N * 4);
    int*   bsumS   = (int*)alloc(64 * 4);
    int*   bsumD   = (int*)alloc(64 * 4);
    int*   eidSrc  = (int*)alloc((size_t)E_ * 4);
    int*   invSrc  = (int*)alloc((size_t)E_ * 4);
    int*   permInv = (int*)alloc((size_t)E_ * 4);
    int*   goffs   = (int*)alloc((size_t)(Gc + 1) * 4);
    float* hE      = (float*)alloc((size_t)E_ * D * 4);
    float* T       = (float*)alloc((size_t)N * TROW * 4);
    float* msg     = (float*)alloc((size_t)E_ * D * 4);
    float* bufA    = (float*)alloc((size_t)N * D * 4);
    float* tmp     = (float*)alloc((size_t)N * D * 4);
    float* stats   = (float*)alloc(32 * 4);

    int nScan = (N + 1023) / 1024;

    k_zero_i<<<(2 * N + 255) / 256, 256, 0, stream>>>(cntS, 2 * N);
    k_hist2<<<(E_ + 255) / 256, 256, 0, stream>>>(srcIdx, dstIdx, cntS, cntD, E_);
    k_scanA<<<nScan, 1024, 0, stream>>>(cntS, offsS, bsumS, N);
    k_scanB<<<1, 64, 0, stream>>>(bsumS, nScan);
    k_scanC<<<nScan, 1024, 0, stream>>>(offsS, cursorS, bsumS, N, E_);
    k_scanA<<<nScan, 1024, 0, stream>>>(cntD, offsD, bsumD, N);
    k_scanB<<<1, 64, 0, stream>>>(bsumD, nScan);
    k_scanC<<<nScan, 1024, 0, stream>>>(offsD, cursorD, bsumD, N, E_);
    k_scatterS<<<(E_ + 255) / 256, 256, 0, stream>>>(srcIdx, cursorS, eidSrc, invSrc, E_);
    k_scatterD<<<(E_ + 255) / 256, 256, 0, stream>>>(dstIdx, invSrc, cursorD, permInv, E_);
    k_he<<<(E_ * D + 255) / 256, 256, 0, stream>>>(ea, ew1, eb1, eidSrc, hE, E_);

    for (int l = 0; l < 3; l++) {
        const float* hin = (l == 0) ? x : bufA;
        float* bnout = (l == 2) ? outHidden : bufA;
        k_T<<<(N + TNB - 1) / TNB, 256, 0, stream>>>(hin, ew2, eb2, T, stats, N);
        k_msg<<<(N + 15) / 16, 256, 0, stream>>>(T, hE, offsS, permInv, msg, N);
        k_agg<<<(N + 15) / 16, 256, 0, stream>>>(hin, msg, offsD,
                                                 root + (size_t)l * 256, cb + (size_t)l * 16,
                                                 tmp, stats, N);
        k_bn<<<((size_t)N * D + 255) / 256, 256, 0, stream>>>(tmp, stats,
                                                              gam + (size_t)l * 16,
                                                              bet + (size_t)l * 16, bnout, N);
    }

    k_gscan<<<1, 512, 0, stream>>>(lens, goffs, Gc);
    k_pool<<<Gc, 64, 0, stream>>>(outHidden, goffs, outPooled, Gc);
    k_fc<<<Gc, 64, 0, stream>>>(outPooled, f1w, f1b, f2w, f2b, outFc, outLsm, Gc);
}

// Round 4
// 466.348 us; speedup vs baseline: 1.3649x; 1.2337x over previous
//
#include <hip/hip_runtime.h>

#define D 16
#define EFD 8
#define TROW 272   // 256 T values (j*16+o) + 16 bias-projection values B[o]
#define NREP 64    // BN-stats replica buffers (breaks atomic same-line contention)

// ---------------- preprocessing: counting sorts of edges by src and by dst ----------------

__global__ void k_zero_i(int* p, int n) {
    int i = blockIdx.x * 256 + threadIdx.x;
    if (i < n) p[i] = 0;
}

__global__ void k_hist2(const int* __restrict__ src, const int* __restrict__ dst,
                        int* __restrict__ cntS, int* __restrict__ cntD, int E_) {
    int e = blockIdx.x * 256 + threadIdx.x;
    if (e < E_) {
        atomicAdd(&cntS[src[e]], 1);
        atomicAdd(&cntD[dst[e]], 1);
    }
}

__global__ void k_scanA(const int* __restrict__ cnt, int* __restrict__ offs,
                        int* __restrict__ bsum, int n) {
    __shared__ int s[1024];
    int i = blockIdx.x * 1024 + threadIdx.x;
    int v = (i < n) ? cnt[i] : 0;
    s[threadIdx.x] = v;
    __syncthreads();
    for (int d = 1; d < 1024; d <<= 1) {
        int t = (threadIdx.x >= d) ? s[threadIdx.x - d] : 0;
        __syncthreads();
        s[threadIdx.x] += t;
        __syncthreads();
    }
    int incl = s[threadIdx.x];
    if (i < n) offs[i] = incl - v;          // exclusive within chunk
    if (threadIdx.x == 1023) bsum[blockIdx.x] = incl;
}

__global__ void k_scanB(int* bsum, int nb) {
    __shared__ int s[64];
    int v = (threadIdx.x < nb) ? bsum[threadIdx.x] : 0;
    s[threadIdx.x] = v;
    __syncthreads();
    for (int d = 1; d < 64; d <<= 1) {
        int t = (threadIdx.x >= d) ? s[threadIdx.x - d] : 0;
        __syncthreads();
        s[threadIdx.x] += t;
        __syncthreads();
    }
    if (threadIdx.x < nb) bsum[threadIdx.x] = s[threadIdx.x] - v;  // exclusive
}

__global__ void k_scanC(int* __restrict__ offs, int* __restrict__ cursor,
                        const int* __restrict__ bsum, int n, int total) {
    int i = blockIdx.x * 1024 + threadIdx.x;
    if (i < n) {
        int v = offs[i] + bsum[blockIdx.x];
        offs[i] = v;
        cursor[i] = v;
    } else if (i == n) {
        offs[n] = total;
    }
}

__global__ void k_scatterS(const int* __restrict__ src, int* __restrict__ cursorS,
                           int* __restrict__ eidSrc, int* __restrict__ invSrc, int E_) {
    int e = blockIdx.x * 256 + threadIdx.x;
    if (e < E_) {
        int p = atomicAdd(&cursorS[src[e]], 1);
        eidSrc[p] = e;
        invSrc[e] = p;
    }
}

// dst counting-sort position, recorded as permInv: src-sorted pos -> dst-sorted pos
__global__ void k_scatterD(const int* __restrict__ dst, const int* __restrict__ invSrc,
                           int* __restrict__ cursorD, int* __restrict__ permInv, int E_) {
    int e = blockIdx.x * 256 + threadIdx.x;
    if (e < E_) {
        int p = atomicAdd(&cursorD[dst[e]], 1);
        permInv[invSrc[e]] = p;
    }
}

// ---------------- edge MLP layer 1 (shared across layers), stored src-sorted ----------------

__global__ void k_he(const float* __restrict__ ea, const float* __restrict__ w1,
                     const float* __restrict__ b1, const int* __restrict__ eidSrc,
                     float* __restrict__ hE, int E_) {
    __shared__ float w1s[EFD * D];
    if (threadIdx.x < EFD * D) w1s[threadIdx.x] = w1[threadIdx.x];
    __syncthreads();
    int t = blockIdx.x * 256 + threadIdx.x;
    int p = t >> 4, o = t & 15;
    if (p < E_) {
        int e = eidSrc[p];
        const float4* a4 = (const float4*)(ea + (size_t)e * EFD);
        float4 x0 = a4[0], x1 = a4[1];
        float s = b1[o];
        s += x0.x * w1s[0 * D + o] + x0.y * w1s[1 * D + o] +
             x0.z * w1s[2 * D + o] + x0.w * w1s[3 * D + o] +
             x1.x * w1s[4 * D + o] + x1.y * w1s[5 * D + o] +
             x1.z * w1s[6 * D + o] + x1.w * w1s[7 * D + o];
        hE[(size_t)p * D + o] = tanhf(s);
    }
}

// ---------------- per-layer: T[n,j,o] = sum_i h[n,i]*w2[j,i*16+o] ; 32 nodes/block, w2 in LDS ----------------

#define TNB 32
#define W2STRIDE 272  // 272 mod 32 == 16 -> 2-way LDS bank aliasing (free)

__global__ void k_T(const float* __restrict__ h, const float* __restrict__ w2,
                    const float* __restrict__ b2, float* __restrict__ T,
                    float* __restrict__ statsR, int n) {
    __shared__ float w2s[D * W2STRIDE];   // [j][i*16+o], padded stride
    __shared__ float b2s[256];
    __shared__ float hs[TNB * D];
    // zero the BN replica stats (NREP*32 floats) using blocks 0..7
    if (blockIdx.x < (NREP * 32 + 255) / 256)
        statsR[blockIdx.x * 256 + threadIdx.x] = 0.f;
    for (int c = threadIdx.x; c < D * 256; c += 256) {
        int j = c >> 8, r = c & 255;
        w2s[j * W2STRIDE + r] = w2[c];
    }
    b2s[threadIdx.x] = b2[threadIdx.x];
    int base = blockIdx.x * TNB;
    for (int c = threadIdx.x; c < TNB * D; c += 256) {
        int node = base + (c >> 4);
        hs[c] = (node < n) ? h[(size_t)node * D + (c & 15)] : 0.f;
    }
    __syncthreads();
    int j = threadIdx.x >> 4, o = threadIdx.x & 15;
    for (int nb = 0; nb < TNB; nb++) {
        int node = base + nb;
        if (node >= n) break;
        float s = 0.f;
#pragma unroll
        for (int i = 0; i < D; i++)
            s += hs[nb * D + i] * w2s[j * W2STRIDE + i * D + o];
        T[(size_t)node * TROW + threadIdx.x] = s;
    }
    int nb2 = threadIdx.x >> 4;
    for (int g = 0; g < TNB / 16; g++) {
        int node = base + g * 16 + nb2;
        if (node < n) {
            float s = 0.f;
#pragma unroll
            for (int i = 0; i < D; i++)
                s += hs[(g * 16 + nb2) * D + i] * b2s[i * D + o];
            T[(size_t)node * TROW + 256 + o] = s;
        }
    }
}

// ---------------- per-layer: per-edge messages, src-ordered compute, dst-ordered scatter write ----------------

__global__ void k_msg(const float* __restrict__ T, const float* __restrict__ hE,
                      const int* __restrict__ offsS, const int* __restrict__ permInv,
                      float* __restrict__ msg, int n) {
    int slot = threadIdx.x >> 4, o = threadIdx.x & 15;
    int s = blockIdx.x * 16 + slot;
    if (s >= n) return;
    const float* Trow = T + (size_t)s * TROW;
    float tr[D];
#pragma unroll
    for (int j = 0; j < D; j++) tr[j] = Trow[j * D + o];
    float tb = Trow[256 + o];
    int p0 = offsS[s], p1 = offsS[s + 1];
    for (int p = p0; p < p1; p++) {
        const float4* he4 = (const float4*)(hE + (size_t)p * D);
        float4 a0 = he4[0], a1 = he4[1], a2 = he4[2], a3 = he4[3];
        float a = tb
            + a0.x * tr[0] + a0.y * tr[1] + a0.z * tr[2] + a0.w * tr[3]
            + a1.x * tr[4] + a1.y * tr[5] + a1.z * tr[6] + a1.w * tr[7]
            + a2.x * tr[8] + a2.y * tr[9] + a2.z * tr[10] + a2.w * tr[11]
            + a3.x * tr[12] + a3.y * tr[13] + a3.z * tr[14] + a3.w * tr[15];
        int q = permInv[p];                       // dst-sorted slot
        msg[(size_t)q * D + o] = a;               // scattered 64B-row store (fire-and-forget)
    }
}

// ---------------- per-layer: dst aggregation (sequential msg read) + root + bias + BN stats ----------------

__global__ void k_agg(const float* __restrict__ h, const float* __restrict__ msg,
                      const int* __restrict__ offsD, const float* __restrict__ root_l,
                      const float* __restrict__ cbias, float* __restrict__ hpre,
                      float* __restrict__ statsR, int n) {
    __shared__ float rootS[D * D];
    __shared__ float red[256], red2[256];
    if (threadIdx.x < D * D) rootS[threadIdx.x] = root_l[threadIdx.x];
    __syncthreads();
    int slot = threadIdx.x >> 4, o = threadIdx.x & 15;
    int node = blockIdx.x * 16 + slot;
    float acc = 0.f;
    if (node < n) {
        int p0 = offsD[node], p1 = offsD[node + 1];
        float sum = 0.f;
        int p = p0;
        for (; p + 4 <= p1; p += 4) {           // unrolled: 4 independent loads in flight
            float a0 = msg[(size_t)(p + 0) * D + o];
            float a1 = msg[(size_t)(p + 1) * D + o];
            float a2 = msg[(size_t)(p + 2) * D + o];
            float a3 = msg[(size_t)(p + 3) * D + o];
            sum += (a0 + a1) + (a2 + a3);
        }
        for (; p < p1; p++) sum += msg[(size_t)p * D + o];
        float deg = (float)((p1 - p0) > 1 ? (p1 - p0) : 1);
        float r = cbias[o];
        const float* hr = h + (size_t)node * D;
#pragma unroll
        for (int i = 0; i < D; i++) r += hr[i] * rootS[i * D + o];
        acc = sum / deg + r;
        hpre[(size_t)node * D + o] = acc;
    }
    red[threadIdx.x] = acc;
    red2[threadIdx.x] = acc * acc;
    __syncthreads();
    for (int off = 128; off >= 16; off >>= 1) {
        if (threadIdx.x < off) {
            red[threadIdx.x] += red[threadIdx.x + off];
            red2[threadIdx.x] += red2[threadIdx.x + off];
        }
        __syncthreads();
    }
    // replica-spread atomics: 64 distinct 128B regions instead of one hot line
    if (threadIdx.x < 32) {
        float v = (threadIdx.x < 16) ? red[threadIdx.x] : red2[threadIdx.x - 16];
        atomicAdd(&statsR[(blockIdx.x & (NREP - 1)) * 32 + threadIdx.x], v);
    }
}

// ---------------- per-layer: BatchNorm apply + tanh (reduces stat replicas in-block) ----------------

__global__ void k_bn(const float* __restrict__ hpre, const float* __restrict__ statsR,
                     const float* __restrict__ gamma, const float* __restrict__ beta,
                     float* __restrict__ out, int n) {
    __shared__ float sstats[32];
    if (threadIdx.x < 32) {
        float a = 0.f;
#pragma unroll 8
        for (int r = 0; r < NREP; r++) a += statsR[r * 32 + threadIdx.x];
        sstats[threadIdx.x] = a;
    }
    __syncthreads();
    int i = blockIdx.x * 256 + threadIdx.x;
    if (i < n * D) {
        int o = i & 15;
        float fn = (float)n;
        float mu = sstats[o] / fn;
        float var = sstats[16 + o] / fn - mu * mu;
        float x = hpre[i];
        float y = (x - mu) * rsqrtf(var + 1e-5f) * gamma[o] + beta[o];
        out[i] = tanhf(y);
    }
}

// ---------------- readout ----------------

__global__ void k_gscan(const int* __restrict__ lengths, int* __restrict__ goffs, int Gc) {
    __shared__ int s[512];
    int v = (threadIdx.x < Gc) ? lengths[threadIdx.x] : 0;
    s[threadIdx.x] = v;
    __syncthreads();
    for (int d = 1; d < 512; d <<= 1) {
        int t = (threadIdx.x >= d) ? s[threadIdx.x - d] : 0;
        __syncthreads();
        s[threadIdx.x] += t;
        __syncthreads();
    }
    if (threadIdx.x < Gc) goffs[threadIdx.x] = s[threadIdx.x] - v;
    if (threadIdx.x == Gc - 1) goffs[Gc] = s[threadIdx.x];
}

__global__ void k_pool(const float* __restrict__ hidden, const int* __restrict__ goffs,
                       float* __restrict__ pooled, int Gc) {
    int g = blockIdx.x;
    int slot = threadIdx.x >> 4, o = threadIdx.x & 15;  // 4 slots x 16 ch
    int n0 = goffs[g], n1 = goffs[g + 1];
    float s = 0.f, mx = -3.402823466e38f, mn = 3.402823466e38f;
    for (int nd = n0 + slot; nd < n1; nd += 4) {
        float v = hidden[(size_t)nd * D + o];
        s += v;
        mx = fmaxf(mx, v);
        mn = fminf(mn, v);
    }
    __shared__ float rs[64], rmx[64], rmn[64];
    rs[threadIdx.x] = s; rmx[threadIdx.x] = mx; rmn[threadIdx.x] = mn;
    __syncthreads();
    for (int off = 32; off >= 16; off >>= 1) {
        if (threadIdx.x < off) {
            rs[threadIdx.x] += rs[threadIdx.x + off];
            rmx[threadIdx.x] = fmaxf(rmx[threadIdx.x], rmx[threadIdx.x + off]);
            rmn[threadIdx.x] = fminf(rmn[threadIdx.x], rmn[threadIdx.x + off]);
        }
        __syncthreads();
    }
    if (threadIdx.x < 16) {
        float cnt = fmaxf((float)(n1 - n0), 1.f);
        float sum = rs[threadIdx.x];
        float* row = pooled + (size_t)g * 64;
        row[threadIdx.x] = sum / cnt;              // mean
        row[16 + threadIdx.x] = rmx[threadIdx.x];  // max
        row[32 + threadIdx.x] = rmn[threadIdx.x];  // min
        row[48 + threadIdx.x] = sum;               // sum
    }
}

__global__ void k_fc(const float* __restrict__ pooled, const float* __restrict__ w1,
                     const float* __restrict__ b1, const float* __restrict__ w2,
                     const float* __restrict__ b2, float* __restrict__ fcOut,
                     float* __restrict__ lsmOut, int Gc) {
    int g = blockIdx.x;
    __shared__ float p[64], t16[16], f10[10];
    __shared__ float mred, lred;
    p[threadIdx.x] = pooled[(size_t)g * 64 + threadIdx.x];
    __syncthreads();
    if (threadIdx.x < 16) {
        float s = b1[threadIdx.x];
        for (int k = 0; k < 64; k++) s += p[k] * w1[k * 16 + threadIdx.x];
        t16[threadIdx.x] = tanhf(s);
    }
    __syncthreads();
    if (threadIdx.x < 10) {
        float s = b2[threadIdx.x];
        for (int o = 0; o < 16; o++) s += t16[o] * w2[o * 10 + threadIdx.x];
        f10[threadIdx.x] = s;
        fcOut[(size_t)g * 10 + threadIdx.x] = s;
    }
    __syncthreads();
    if (threadIdx.x == 0) {
        float m = f10[0];
        for (int c = 1; c < 10; c++) m = fmaxf(m, f10[c]);
        float se = 0.f;
        for (int c = 0; c < 10; c++) se += expf(f10[c] - m);
        mred = m;
        lred = logf(se);
    }
    __syncthreads();
    if (threadIdx.x < 10)
        lsmOut[(size_t)g * 10 + threadIdx.x] = f10[threadIdx.x] - mred - lred;
}

// ---------------- host ----------------

extern "C" void kernel_launch(void* const* d_in, const int* in_sizes, int n_in,
                              void* d_out, int out_size, void* d_ws, size_t ws_size,
                              hipStream_t stream) {
    const float* x    = (const float*)d_in[0];
    const float* ea   = (const float*)d_in[1];
    const float* ew1  = (const float*)d_in[2];
    const float* eb1  = (const float*)d_in[3];
    const float* ew2  = (const float*)d_in[4];
    const float* eb2  = (const float*)d_in[5];
    const float* root = (const float*)d_in[6];
    const float* cb   = (const float*)d_in[7];
    const float* gam  = (const float*)d_in[8];
    const float* bet  = (const float*)d_in[9];
    const float* f1w  = (const float*)d_in[10];
    const float* f1b  = (const float*)d_in[11];
    const float* f2w  = (const float*)d_in[12];
    const float* f2b  = (const float*)d_in[13];
    const int* eidx   = (const int*)d_in[14];
    const int* lens   = (const int*)d_in[15];

    int N  = in_sizes[0] / D;
    int E_ = in_sizes[1] / EFD;
    int Gc = in_sizes[15];
    const int* srcIdx = eidx;
    const int* dstIdx = eidx + E_;

    float* outHidden = (float*)d_out;
    float* outPooled = outHidden + (size_t)N * D;
    float* outFc     = outPooled + (size_t)Gc * 4 * D;
    float* outLsm    = outFc + (size_t)Gc * 10;

    char* wsp = (char*)d_ws;
    size_t off = 0;
    auto alloc = [&](size_t bytes) -> void* {
        void* p = wsp + off;
        off = (off + bytes + 255) & ~(size_t)255;
        return p;
    };
    int*   cntS    = (int*)alloc((size_t)2 * N * 4);   // cntS | cntD contiguous
    int*   cntD    = cntS + N;
    int*   offsS   = (int*)alloc((size_t)(N + 1) * 4);
    int*   offsD   = (int*)alloc((size_t)(N + 1) * 4);
    int*   cursorS = (int*)alloc((size_t)N * 4);
    int*   cursorD = (int*)alloc((size_t)N * 4);
    int*   bsumS   = (int*)alloc(64 * 4);
    int*   bsumD   = (int*)alloc(64 * 4);
    int*   eidSrc  = (int*)alloc((size_t)E_ * 4);
    int*   invSrc  = (int*)alloc((size_t)E_ * 4);
    int*   permInv = (int*)alloc((size_t)E_ * 4);
    int*   goffs   = (int*)alloc((size_t)(Gc + 1) * 4);
    float* hE      = (float*)alloc((size_t)E_ * D * 4);
    float* T       = (float*)alloc((size_t)N * TROW * 4);
    float* msg     = (float*)alloc((size_t)E_ * D * 4);
    float* bufA    = (float*)alloc((size_t)N * D * 4);
    float* tmp     = (float*)alloc((size_t)N * D * 4);
    float* statsR  = (float*)alloc((size_t)NREP * 32 * 4);

    int nScan = (N + 1023) / 1024;

    k_zero_i<<<(2 * N + 255) / 256, 256, 0, stream>>>(cntS, 2 * N);
    k_hist2<<<(E_ + 255) / 256, 256, 0, stream>>>(srcIdx, dstIdx, cntS, cntD, E_);
    k_scanA<<<nScan, 1024, 0, stream>>>(cntS, offsS, bsumS, N);
    k_scanB<<<1, 64, 0, stream>>>(bsumS, nScan);
    k_scanC<<<nScan, 1024, 0, stream>>>(offsS, cursorS, bsumS, N, E_);
    k_scanA<<<nScan, 1024, 0, stream>>>(cntD, offsD, bsumD, N);
    k_scanB<<<1, 64, 0, stream>>>(bsumD, nScan);
    k_scanC<<<nScan, 1024, 0, stream>>>(offsD, cursorD, bsumD, N, E_);
    k_scatterS<<<(E_ + 255) / 256, 256, 0, stream>>>(srcIdx, cursorS, eidSrc, invSrc, E_);
    k_scatterD<<<(E_ + 255) / 256, 256, 0, stream>>>(dstIdx, invSrc, cursorD, permInv, E_);
    k_he<<<(E_ * D + 255) / 256, 256, 0, stream>>>(ea, ew1, eb1, eidSrc, hE, E_);

    for (int l = 0; l < 3; l++) {
        const float* hin = (l == 0) ? x : bufA;
        float* bnout = (l == 2) ? outHidden : bufA;
        k_T<<<(N + TNB - 1) / TNB, 256, 0, stream>>>(hin, ew2, eb2, T, statsR, N);
        k_msg<<<(N + 15) / 16, 256, 0, stream>>>(T, hE, offsS, permInv, msg, N);
        k_agg<<<(N + 15) / 16, 256, 0, stream>>>(hin, msg, offsD,
                                                 root + (size_t)l * 256, cb + (size_t)l * 16,
                                                 tmp, statsR, N);
        k_bn<<<((size_t)N * D + 255) / 256, 256, 0, stream>>>(tmp, statsR,
                                                              gam + (size_t)l * 16,
                                                              bet + (size_t)l * 16, bnout, N);
    }

    k_gscan<<<1, 512, 0, stream>>>(lens, goffs, Gc);
    k_pool<<<Gc, 64, 0, stream>>>(outHidden, goffs, outPooled, Gc);
    k_fc<<<Gc, 64, 0, stream>>>(outPooled, f1w, f1b, f2w, f2b, outFc, outLsm, Gc);
}

// Round 5
// 417.838 us; speedup vs baseline: 1.5233x; 1.1161x over previous
//
#include <hip/hip_runtime.h>

#define D 16
#define EFD 8
#define TROW 272   // 256 T values (j*16+o) + 16 bias-projection values B[o]
#define NREP 64    // BN-stats replica buffers (breaks atomic same-line contention)

// ---------------- zero scratch (cnt arrays + all 3 BN stat slots) ----------------

__global__ void k_zero2(int* a, int na, float* b, int nb) {
    int i = blockIdx.x * 256 + threadIdx.x;
    if (i < na) a[i] = 0;
    if (i < nb) b[i] = 0.f;
}

// ---------------- rank: one atomic per edge per side; cnt becomes the histogram ----------------

__global__ void k_rank2(const int* __restrict__ src, const int* __restrict__ dst,
                        int* __restrict__ cntS, int* __restrict__ cntD,
                        int* __restrict__ rankS, int* __restrict__ rankD, int E_) {
    int e = blockIdx.x * 256 + threadIdx.x;
    if (e < E_) {
        rankS[e] = atomicAdd(&cntS[src[e]], 1);
        rankD[e] = atomicAdd(&cntD[dst[e]], 1);
    }
}

// ---------------- scans over cntS|cntD (both halves in one launch) ----------------

__global__ void k_scanA2(const int* __restrict__ cnt2, int* __restrict__ offs2,
                         int* __restrict__ bsum2, int n, int nScan) {
    __shared__ int s[1024];
    int half = blockIdx.x / nScan;
    int blk  = blockIdx.x % nScan;
    const int* c = cnt2 + (size_t)half * n;
    int* of = offs2 + (size_t)half * (n + 1);
    int* bs = bsum2 + half * 64;
    int i = blk * 1024 + threadIdx.x;
    int v = (i < n) ? c[i] : 0;
    s[threadIdx.x] = v;
    __syncthreads();
    for (int d = 1; d < 1024; d <<= 1) {
        int t = (threadIdx.x >= d) ? s[threadIdx.x - d] : 0;
        __syncthreads();
        s[threadIdx.x] += t;
        __syncthreads();
    }
    int incl = s[threadIdx.x];
    if (i < n) of[i] = incl - v;            // exclusive within chunk
    if (threadIdx.x == 1023) bs[blk] = incl;
}

__global__ void k_scanB2(int* bsum2, int nb) {
    __shared__ int s[64];
    int* bs = bsum2 + blockIdx.x * 64;
    int v = (threadIdx.x < nb) ? bs[threadIdx.x] : 0;
    s[threadIdx.x] = v;
    __syncthreads();
    for (int d = 1; d < 64; d <<= 1) {
        int t = (threadIdx.x >= d) ? s[threadIdx.x - d] : 0;
        __syncthreads();
        s[threadIdx.x] += t;
        __syncthreads();
    }
    if (threadIdx.x < nb) bs[threadIdx.x] = s[threadIdx.x] - v;  // exclusive
}

__global__ void k_scanC2(int* __restrict__ offs2, const int* __restrict__ bsum2,
                         int n, int nScan, int total) {
    int half = blockIdx.x / nScan;
    int blk  = blockIdx.x % nScan;
    int* of = offs2 + (size_t)half * (n + 1);
    const int* bs = bsum2 + half * 64;
    int i = blk * 1024 + threadIdx.x;
    if (i < n) of[i] += bs[blk];
    else if (i == n) of[n] = total;
}

// ---------------- place: NO atomics; builds src-sorted edge list + permInv in one pass ----------------

__global__ void k_place2(const int* __restrict__ src, const int* __restrict__ dst,
                         const int* __restrict__ rankS, const int* __restrict__ rankD,
                         const int* __restrict__ offsS, const int* __restrict__ offsD,
                         int* __restrict__ eidSrc, int* __restrict__ permInv, int E_) {
    int e = blockIdx.x * 256 + threadIdx.x;
    if (e < E_) {
        int p = offsS[src[e]] + rankS[e];   // src-sorted position
        int q = offsD[dst[e]] + rankD[e];   // dst-sorted position
        eidSrc[p] = e;
        permInv[p] = q;
    }
}

// ---------------- edge MLP layer 1 (shared across layers), stored src-sorted ----------------

__global__ void k_he(const float* __restrict__ ea, const float* __restrict__ w1,
                     const float* __restrict__ b1, const int* __restrict__ eidSrc,
                     float* __restrict__ hE, int E_) {
    __shared__ float w1s[EFD * D];
    if (threadIdx.x < EFD * D) w1s[threadIdx.x] = w1[threadIdx.x];
    __syncthreads();
    int t = blockIdx.x * 256 + threadIdx.x;
    int p = t >> 4, o = t & 15;
    if (p < E_) {
        int e = eidSrc[p];
        const float4* a4 = (const float4*)(ea + (size_t)e * EFD);
        float4 x0 = a4[0], x1 = a4[1];
        float s = b1[o];
        s += x0.x * w1s[0 * D + o] + x0.y * w1s[1 * D + o] +
             x0.z * w1s[2 * D + o] + x0.w * w1s[3 * D + o] +
             x1.x * w1s[4 * D + o] + x1.y * w1s[5 * D + o] +
             x1.z * w1s[6 * D + o] + x1.w * w1s[7 * D + o];
        hE[(size_t)p * D + o] = tanhf(s);
    }
}

// ---------------- per-layer: fused [BN+tanh of prev layer] + T precompute ----------------
// T[n,j,o] = sum_i h[n,i]*w2[j,i*16+o]; 32 nodes/block, w2 in LDS.
// useBN: hin is hpre of prev layer; apply BN(statsPrev)+tanh, write h to hout, use it.

#define TNB 32
#define W2STRIDE 272  // 272 mod 32 == 16 -> 2-way LDS bank aliasing (free)

__global__ void k_T(const float* __restrict__ hin, const float* __restrict__ statsPrev,
                    const float* __restrict__ gamma, const float* __restrict__ beta,
                    float* __restrict__ hout, const float* __restrict__ w2,
                    const float* __restrict__ b2, float* __restrict__ T,
                    int n, int useBN) {
    __shared__ float w2s[D * W2STRIDE];   // [j][i*16+o], padded stride
    __shared__ float b2s[256];
    __shared__ float hs[TNB * D];
    __shared__ float sstats[32];
    for (int c = threadIdx.x; c < D * 256; c += 256) {
        int j = c >> 8, r = c & 255;
        w2s[j * W2STRIDE + r] = w2[c];
    }
    b2s[threadIdx.x] = b2[threadIdx.x];
    if (useBN && threadIdx.x < 32) {
        float a = 0.f;
#pragma unroll 8
        for (int r = 0; r < NREP; r++) a += statsPrev[r * 32 + threadIdx.x];
        sstats[threadIdx.x] = a;
    }
    __syncthreads();
    int base = blockIdx.x * TNB;
    float fn = (float)n;
    for (int c = threadIdx.x; c < TNB * D; c += 256) {
        int node = base + (c >> 4);
        int o = c & 15;
        float hv = 0.f;
        if (node < n) {
            float xin = hin[(size_t)node * D + o];
            if (useBN) {
                float mu = sstats[o] / fn;
                float var = sstats[16 + o] / fn - mu * mu;
                hv = tanhf((xin - mu) * rsqrtf(var + 1e-5f) * gamma[o] + beta[o]);
                hout[(size_t)node * D + o] = hv;
            } else {
                hv = xin;
            }
        }
        hs[c] = hv;
    }
    __syncthreads();
    int j = threadIdx.x >> 4, o = threadIdx.x & 15;
    for (int nb = 0; nb < TNB; nb++) {
        int node = base + nb;
        if (node >= n) break;
        float s = 0.f;
#pragma unroll
        for (int i = 0; i < D; i++)
            s += hs[nb * D + i] * w2s[j * W2STRIDE + i * D + o];
        T[(size_t)node * TROW + threadIdx.x] = s;
    }
    int nb2 = threadIdx.x >> 4;
    for (int g = 0; g < TNB / 16; g++) {
        int node = base + g * 16 + nb2;
        if (node < n) {
            float s = 0.f;
#pragma unroll
            for (int i = 0; i < D; i++)
                s += hs[(g * 16 + nb2) * D + i] * b2s[i * D + o];
            T[(size_t)node * TROW + 256 + o] = s;
        }
    }
}

// ---------------- per-layer: per-edge messages, src-ordered compute, dst-ordered scatter write ----------------

__global__ void k_msg(const float* __restrict__ T, const float* __restrict__ hE,
                      const int* __restrict__ offsS, const int* __restrict__ permInv,
                      float* __restrict__ msg, int n) {
    int slot = threadIdx.x >> 4, o = threadIdx.x & 15;
    int s = blockIdx.x * 16 + slot;
    if (s >= n) return;
    const float* Trow = T + (size_t)s * TROW;
    float tr[D];
#pragma unroll
    for (int j = 0; j < D; j++) tr[j] = Trow[j * D + o];
    float tb = Trow[256 + o];
    int p0 = offsS[s], p1 = offsS[s + 1];
    for (int p = p0; p < p1; p++) {
        const float4* he4 = (const float4*)(hE + (size_t)p * D);
        float4 a0 = he4[0], a1 = he4[1], a2 = he4[2], a3 = he4[3];
        float a = tb
            + a0.x * tr[0] + a0.y * tr[1] + a0.z * tr[2] + a0.w * tr[3]
            + a1.x * tr[4] + a1.y * tr[5] + a1.z * tr[6] + a1.w * tr[7]
            + a2.x * tr[8] + a2.y * tr[9] + a2.z * tr[10] + a2.w * tr[11]
            + a3.x * tr[12] + a3.y * tr[13] + a3.z * tr[14] + a3.w * tr[15];
        int q = permInv[p];                       // dst-sorted slot
        msg[(size_t)q * D + o] = a;               // scattered 64B-row store (fire-and-forget)
    }
}

// ---------------- per-layer: dst aggregation (sequential msg read) + root + bias + BN stats ----------------

__global__ void k_agg(const float* __restrict__ h, const float* __restrict__ msg,
                      const int* __restrict__ offsD, const float* __restrict__ root_l,
                      const float* __restrict__ cbias, float* __restrict__ hpre,
                      float* __restrict__ statsR, int n) {
    __shared__ float rootS[D * D];
    __shared__ float red[256], red2[256];
    if (threadIdx.x < D * D) rootS[threadIdx.x] = root_l[threadIdx.x];
    __syncthreads();
    int slot = threadIdx.x >> 4, o = threadIdx.x & 15;
    int node = blockIdx.x * 16 + slot;
    float acc = 0.f;
    if (node < n) {
        int p0 = offsD[node], p1 = offsD[node + 1];
        float sum = 0.f;
        int p = p0;
        for (; p + 4 <= p1; p += 4) {           // unrolled: 4 independent loads in flight
            float a0 = msg[(size_t)(p + 0) * D + o];
            float a1 = msg[(size_t)(p + 1) * D + o];
            float a2 = msg[(size_t)(p + 2) * D + o];
            float a3 = msg[(size_t)(p + 3) * D + o];
            sum += (a0 + a1) + (a2 + a3);
        }
        for (; p < p1; p++) sum += msg[(size_t)p * D + o];
        float deg = (float)((p1 - p0) > 1 ? (p1 - p0) : 1);
        float r = cbias[o];
        const float* hr = h + (size_t)node * D;
#pragma unroll
        for (int i = 0; i < D; i++) r += hr[i] * rootS[i * D + o];
        acc = sum / deg + r;
        hpre[(size_t)node * D + o] = acc;
    }
    red[threadIdx.x] = acc;
    red2[threadIdx.x] = acc * acc;
    __syncthreads();
    for (int off = 128; off >= 16; off >>= 1) {
        if (threadIdx.x < off) {
            red[threadIdx.x] += red[threadIdx.x + off];
            red2[threadIdx.x] += red2[threadIdx.x + off];
        }
        __syncthreads();
    }
    // replica-spread atomics: 64 distinct regions instead of one hot line
    if (threadIdx.x < 32) {
        float v = (threadIdx.x < 16) ? red[threadIdx.x] : red2[threadIdx.x - 16];
        atomicAdd(&statsR[(blockIdx.x & (NREP - 1)) * 32 + threadIdx.x], v);
    }
}

// ---------------- final layer: BatchNorm apply + tanh (writes hidden output) ----------------

__global__ void k_bn(const float* __restrict__ hpre, const float* __restrict__ statsR,
                     const float* __restrict__ gamma, const float* __restrict__ beta,
                     float* __restrict__ out, int n) {
    __shared__ float sstats[32];
    if (threadIdx.x < 32) {
        float a = 0.f;
#pragma unroll 8
        for (int r = 0; r < NREP; r++) a += statsR[r * 32 + threadIdx.x];
        sstats[threadIdx.x] = a;
    }
    __syncthreads();
    int i = blockIdx.x * 256 + threadIdx.x;
    if (i < n * D) {
        int o = i & 15;
        float fn = (float)n;
        float mu = sstats[o] / fn;
        float var = sstats[16 + o] / fn - mu * mu;
        float x = hpre[i];
        float y = (x - mu) * rsqrtf(var + 1e-5f) * gamma[o] + beta[o];
        out[i] = tanhf(y);
    }
}

// ---------------- fused readout: per-graph scan + pool + MLP + log_softmax ----------------

__global__ void k_readout(const float* __restrict__ hidden, const int* __restrict__ lengths,
                          const float* __restrict__ w1, const float* __restrict__ b1,
                          const float* __restrict__ w2, const float* __restrict__ b2,
                          float* __restrict__ outPooled, float* __restrict__ fcOut,
                          float* __restrict__ lsmOut, int Gc) {
    __shared__ int sl[512];
    int tid = threadIdx.x;
    int g = blockIdx.x;
    // redundant per-block scan of lengths (Gc <= 512)
    int v = (tid < Gc) ? lengths[tid] : 0;
    sl[tid] = v;
    __syncthreads();
    for (int d = 1; d < 512; d <<= 1) {
        int t = (tid >= d) ? sl[tid - d] : 0;
        __syncthreads();
        sl[tid] += t;
        __syncthreads();
    }
    int n1 = sl[g];
    int n0 = n1 - lengths[g];
    // pool: 32 slots x 16 channels
    int slot = tid >> 4, o = tid & 15;
    float s = 0.f, mx = -3.402823466e38f, mn = 3.402823466e38f;
    for (int nd = n0 + slot; nd < n1; nd += 32) {
        float x = hidden[(size_t)nd * D + o];
        s += x;
        mx = fmaxf(mx, x);
        mn = fminf(mn, x);
    }
    __shared__ float rs[512], rmx[512], rmn[512];
    rs[tid] = s; rmx[tid] = mx; rmn[tid] = mn;
    __syncthreads();
    for (int off = 256; off >= 16; off >>= 1) {
        if (tid < off) {
            rs[tid] += rs[tid + off];
            rmx[tid] = fmaxf(rmx[tid], rmx[tid + off]);
            rmn[tid] = fminf(rmn[tid], rmn[tid + off]);
        }
        __syncthreads();
    }
    __shared__ float p64[64], t16[16], f10[10];
    __shared__ float mred, lred;
    if (tid < 16) {
        float cnt = fmaxf((float)(n1 - n0), 1.f);
        float sum = rs[tid];
        float* row = outPooled + (size_t)g * 64;
        float mean = sum / cnt;
        p64[tid] = mean;          row[tid] = mean;
        p64[16 + tid] = rmx[tid]; row[16 + tid] = rmx[tid];
        p64[32 + tid] = rmn[tid]; row[32 + tid] = rmn[tid];
        p64[48 + tid] = sum;      row[48 + tid] = sum;
    }
    __syncthreads();
    if (tid < 16) {
        float a = b1[tid];
        for (int k = 0; k < 64; k++) a += p64[k] * w1[k * 16 + tid];
        t16[tid] = tanhf(a);
    }
    __syncthreads();
    if (tid < 10) {
        float a = b2[tid];
        for (int oo = 0; oo < 16; oo++) a += t16[oo] * w2[oo * 10 + tid];
        f10[tid] = a;
        fcOut[(size_t)g * 10 + tid] = a;
    }
    __syncthreads();
    if (tid == 0) {
        float m = f10[0];
        for (int c = 1; c < 10; c++) m = fmaxf(m, f10[c]);
        float se = 0.f;
        for (int c = 0; c < 10; c++) se += expf(f10[c] - m);
        mred = m;
        lred = logf(se);
    }
    __syncthreads();
    if (tid < 10)
        lsmOut[(size_t)g * 10 + tid] = f10[tid] - mred - lred;
}

// ---------------- host ----------------

extern "C" void kernel_launch(void* const* d_in, const int* in_sizes, int n_in,
                              void* d_out, int out_size, void* d_ws, size_t ws_size,
                              hipStream_t stream) {
    const float* x    = (const float*)d_in[0];
    const float* ea   = (const float*)d_in[1];
    const float* ew1  = (const float*)d_in[2];
    const float* eb1  = (const float*)d_in[3];
    const float* ew2  = (const float*)d_in[4];
    const float* eb2  = (const float*)d_in[5];
    const float* root = (const float*)d_in[6];
    const float* cb   = (const float*)d_in[7];
    const float* gam  = (const float*)d_in[8];
    const float* bet  = (const float*)d_in[9];
    const float* f1w  = (const float*)d_in[10];
    const float* f1b  = (const float*)d_in[11];
    const float* f2w  = (const float*)d_in[12];
    const float* f2b  = (const float*)d_in[13];
    const int* eidx   = (const int*)d_in[14];
    const int* lens   = (const int*)d_in[15];

    int N  = in_sizes[0] / D;
    int E_ = in_sizes[1] / EFD;
    int Gc = in_sizes[15];
    const int* srcIdx = eidx;
    const int* dstIdx = eidx + E_;

    float* outHidden = (float*)d_out;
    float* outPooled = outHidden + (size_t)N * D;
    float* outFc     = outPooled + (size_t)Gc * 4 * D;
    float* outLsm    = outFc + (size_t)Gc * 10;

    char* wsp = (char*)d_ws;
    size_t off = 0;
    auto alloc = [&](size_t bytes) -> void* {
        void* p = wsp + off;
        off = (off + bytes + 255) & ~(size_t)255;
        return p;
    };
    int*   cnt2    = (int*)alloc((size_t)2 * N * 4);          // cntS | cntD
    int*   offs2   = (int*)alloc((size_t)2 * (N + 1) * 4);    // offsS | offsD
    int*   bsum2   = (int*)alloc(128 * 4);
    int*   rankS   = (int*)alloc((size_t)E_ * 4);
    int*   rankD   = (int*)alloc((size_t)E_ * 4);
    int*   eidSrc  = (int*)alloc((size_t)E_ * 4);
    int*   permInv = (int*)alloc((size_t)E_ * 4);
    float* hE      = (float*)alloc((size_t)E_ * D * 4);
    float* T       = (float*)alloc((size_t)N * TROW * 4);
    float* msg     = (float*)alloc((size_t)E_ * D * 4);
    float* bufA    = (float*)alloc((size_t)N * D * 4);
    float* tmp     = (float*)alloc((size_t)N * D * 4);
    float* statsR3 = (float*)alloc((size_t)3 * NREP * 32 * 4); // one slot per layer

    int* offsS = offs2;
    int* offsD = offs2 + (N + 1);
    int nScan = (N + 1023) / 1024;

    k_zero2<<<(2 * N + 255) / 256, 256, 0, stream>>>(cnt2, 2 * N, statsR3, 3 * NREP * 32);
    k_rank2<<<(E_ + 255) / 256, 256, 0, stream>>>(srcIdx, dstIdx, cnt2, cnt2 + N,
                                                  rankS, rankD, E_);
    k_scanA2<<<2 * nScan, 1024, 0, stream>>>(cnt2, offs2, bsum2, N, nScan);
    k_scanB2<<<2, 64, 0, stream>>>(bsum2, nScan);
    k_scanC2<<<2 * nScan, 1024, 0, stream>>>(offs2, bsum2, N, nScan, E_);
    k_place2<<<(E_ + 255) / 256, 256, 0, stream>>>(srcIdx, dstIdx, rankS, rankD,
                                                   offsS, offsD, eidSrc, permInv, E_);
    k_he<<<(E_ * D + 255) / 256, 256, 0, stream>>>(ea, ew1, eb1, eidSrc, hE, E_);

    for (int l = 0; l < 3; l++) {
        const float* hin  = (l == 0) ? x : tmp;               // x or hpre of prev layer
        const float* hroot = (l == 0) ? x : bufA;             // h for root term
        float* statsCur = statsR3 + (size_t)l * NREP * 32;
        const float* statsPrev = statsR3 + (size_t)(l - 1) * NREP * 32;
        k_T<<<(N + TNB - 1) / TNB, 256, 0, stream>>>(
            hin, (l == 0) ? nullptr : statsPrev,
            (l == 0) ? nullptr : gam + (size_t)(l - 1) * 16,
            (l == 0) ? nullptr : bet + (size_t)(l - 1) * 16,
            bufA, ew2, eb2, T, N, (l == 0) ? 0 : 1);
        k_msg<<<(N + 15) / 16, 256, 0, stream>>>(T, hE, offsS, permInv, msg, N);
        k_agg<<<(N + 15) / 16, 256, 0, stream>>>(hroot, msg, offsD,
                                                 root + (size_t)l * 256, cb + (size_t)l * 16,
                                                 tmp, statsCur, N);
    }
    k_bn<<<((size_t)N * D + 255) / 256, 256, 0, stream>>>(tmp, statsR3 + (size_t)2 * NREP * 32,
                                                          gam + 32, bet + 32, outHidden, N);

    k_readout<<<Gc, 512, 0, stream>>>(outHidden, lens, f1w, f1b, f2w, f2b,
                                      outPooled, outFc, outLsm, Gc);
}

// Round 6
// 372.001 us; speedup vs baseline: 1.7110x; 1.1232x over previous
//
#include <hip/hip_runtime.h>

#define D 16
#define EFD 8
#define NREP 64       // BN-stats replica buffers (breaks atomic same-line contention)
#define W2STRIDE 272  // 272 mod 32 == 16 -> 2-way LDS bank aliasing (free)

// ---------------- zero scratch (cnt arrays + all 3 BN stat slots) ----------------

__global__ void k_zero2(int* a, int na, float* b, int nb) {
    int i = blockIdx.x * 256 + threadIdx.x;
    if (i < na) a[i] = 0;
    if (i < nb) b[i] = 0.f;
}

// ---------------- rank: one atomic per edge per side; cnt becomes the histogram ----------------

__global__ void k_rank2(const int* __restrict__ src, const int* __restrict__ dst,
                        int* __restrict__ cntS, int* __restrict__ cntD,
                        int* __restrict__ rankS, int* __restrict__ rankD, int E_) {
    int e = blockIdx.x * 256 + threadIdx.x;
    if (e < E_) {
        rankS[e] = atomicAdd(&cntS[src[e]], 1);
        rankD[e] = atomicAdd(&cntD[dst[e]], 1);
    }
}

// ---------------- scans over cntS|cntD (both halves in one launch) ----------------

__global__ void k_scanA2(const int* __restrict__ cnt2, int* __restrict__ offs2,
                         int* __restrict__ bsum2, int n, int nScan) {
    __shared__ int s[1024];
    int half = blockIdx.x / nScan;
    int blk  = blockIdx.x % nScan;
    const int* c = cnt2 + (size_t)half * n;
    int* of = offs2 + (size_t)half * (n + 1);
    int* bs = bsum2 + half * 64;
    int i = blk * 1024 + threadIdx.x;
    int v = (i < n) ? c[i] : 0;
    s[threadIdx.x] = v;
    __syncthreads();
    for (int d = 1; d < 1024; d <<= 1) {
        int t = (threadIdx.x >= d) ? s[threadIdx.x - d] : 0;
        __syncthreads();
        s[threadIdx.x] += t;
        __syncthreads();
    }
    int incl = s[threadIdx.x];
    if (i < n) of[i] = incl - v;            // exclusive within chunk
    if (threadIdx.x == 1023) bs[blk] = incl;
}

// scanC with the 64-entry block-sum scan folded in (done redundantly per block)
__global__ void k_scanC2(int* __restrict__ offs2, const int* __restrict__ bsum2,
                         int n, int nScan, int total) {
    __shared__ int s[64];
    int half = blockIdx.x / nScan;
    int blk  = blockIdx.x % nScan;
    int* of = offs2 + (size_t)half * (n + 1);
    const int* bs = bsum2 + half * 64;
    if (threadIdx.x < 64) s[threadIdx.x] = (threadIdx.x < nScan) ? bs[threadIdx.x] : 0;
    __syncthreads();
    if (threadIdx.x < 64) {
        for (int d = 1; d < 64; d <<= 1) {
            int t = (threadIdx.x >= d) ? s[threadIdx.x - d] : 0;
            __syncthreads();
            s[threadIdx.x] += t;
            __syncthreads();
        }
    } else {
        for (int d = 1; d < 64; d <<= 1) { __syncthreads(); __syncthreads(); }
    }
    int base = (blk == 0) ? 0 : s[blk - 1];
    int i = blk * 1024 + threadIdx.x;
    if (i < n) of[i] += base;
    else if (i == n) of[n] = total;
}

// ---------------- fused place + edge-MLP + permInv: NO atomics ----------------
// For edge e: p = src-sorted pos, q = dst-sorted pos. Writes hE[p] (edge MLP output,
// src-sorted) and permInv[p] = q in one pass. ea read is coalesced; writes scattered.

__global__ void k_place_he(const int* __restrict__ src, const int* __restrict__ dst,
                           const int* __restrict__ rankS, const int* __restrict__ rankD,
                           const int* __restrict__ offsS, const int* __restrict__ offsD,
                           const float* __restrict__ ea, const float* __restrict__ w1,
                           const float* __restrict__ b1,
                           float* __restrict__ hE, int* __restrict__ permInv, int E_) {
    __shared__ float w1s[EFD * D];
    __shared__ float b1s[D];
    if (threadIdx.x < EFD * D) w1s[threadIdx.x] = w1[threadIdx.x];
    if (threadIdx.x < D) b1s[threadIdx.x] = b1[threadIdx.x];
    __syncthreads();
    int e = blockIdx.x * 256 + threadIdx.x;
    if (e >= E_) return;
    int p = offsS[src[e]] + rankS[e];
    int q = offsD[dst[e]] + rankD[e];
    permInv[p] = q;
    const float4* a4 = (const float4*)(ea + (size_t)e * EFD);
    float4 x0 = a4[0], x1 = a4[1];
    float out[D];
#pragma unroll
    for (int o = 0; o < D; o++) {
        float s = b1s[o];
        s += x0.x * w1s[0 * D + o] + x0.y * w1s[1 * D + o] +
             x0.z * w1s[2 * D + o] + x0.w * w1s[3 * D + o] +
             x1.x * w1s[4 * D + o] + x1.y * w1s[5 * D + o] +
             x1.z * w1s[6 * D + o] + x1.w * w1s[7 * D + o];
        out[o] = tanhf(s);
    }
    float4* h4 = (float4*)(hE + (size_t)p * D);
#pragma unroll
    for (int v = 0; v < 4; v++)
        h4[v] = make_float4(out[v * 4 + 0], out[v * 4 + 1], out[v * 4 + 2], out[v * 4 + 3]);
}

// ---------------- per-layer FUSED: [BN+tanh prev] + T-tile (LDS only) + messages ----------------
// Block owns 16 src nodes. T[s,j,o] = sum_i h[s,i]*w2[j,i*16+o] computed into LDS,
// never hits global. Messages written dst-sorted (scatter via permInv).

__global__ void k_Tmsg(const float* __restrict__ hin, const float* __restrict__ statsPrev,
                       const float* __restrict__ gamma, const float* __restrict__ beta,
                       float* __restrict__ hout, const float* __restrict__ w2,
                       const float* __restrict__ b2, const float* __restrict__ hE,
                       const int* __restrict__ offsS, const int* __restrict__ permInv,
                       float* __restrict__ msg, int n, int useBN) {
    __shared__ float w2s[D * W2STRIDE];   // [j][i*16+o]
    __shared__ float b2s[256];
    __shared__ float hs[16 * D];
    __shared__ float Tt[16 * W2STRIDE];   // [slot][j*16+o | 256+o]
    __shared__ float sstats[32];
    int tid = threadIdx.x;
    for (int c = tid; c < D * 256; c += 256) {
        int j = c >> 8, r = c & 255;
        w2s[j * W2STRIDE + r] = w2[c];
    }
    b2s[tid] = b2[tid];
    if (useBN && tid < 32) {
        float a = 0.f;
#pragma unroll 8
        for (int r = 0; r < NREP; r++) a += statsPrev[r * 32 + tid];
        sstats[tid] = a;
    }
    __syncthreads();
    int base = blockIdx.x * 16;
    float fn = (float)n;
    {   // stage h rows (apply BN+tanh of previous layer if needed)
        int node = base + (tid >> 4);
        int o = tid & 15;
        float hv = 0.f;
        if (node < n) {
            float xin = hin[(size_t)node * D + o];
            if (useBN) {
                float mu = sstats[o] / fn;
                float var = sstats[16 + o] / fn - mu * mu;
                hv = tanhf((xin - mu) * rsqrtf(var + 1e-5f) * gamma[o] + beta[o]);
                hout[(size_t)node * D + o] = hv;
            } else {
                hv = xin;
            }
        }
        hs[tid] = hv;
    }
    __syncthreads();
    {   // T-tile: thread c computes Tt[nb][c] for nb=0..15 (c = j*16+o)
        int j = tid >> 4, o = tid & 15;
#pragma unroll 4
        for (int nb = 0; nb < 16; nb++) {
            float s = 0.f;
#pragma unroll
            for (int i = 0; i < D; i++)
                s += hs[nb * D + i] * w2s[j * W2STRIDE + i * D + o];
            Tt[nb * W2STRIDE + tid] = s;
        }
        // bias projection: thread (nb2, o) computes Tt[nb2][256+o]
        int nb2 = tid >> 4;
        float s = 0.f;
#pragma unroll
        for (int i = 0; i < D; i++)
            s += hs[nb2 * D + i] * b2s[i * D + o];
        Tt[nb2 * W2STRIDE + 256 + o] = s;
    }
    __syncthreads();
    {   // messages: thread (slot, o), T row register-resident from LDS
        int slot = tid >> 4, o = tid & 15;
        int s = base + slot;
        if (s >= n) return;
        float tr[D];
#pragma unroll
        for (int j = 0; j < D; j++) tr[j] = Tt[slot * W2STRIDE + j * D + o];
        float tb = Tt[slot * W2STRIDE + 256 + o];
        int p0 = offsS[s], p1 = offsS[s + 1];
        for (int p = p0; p < p1; p++) {
            const float4* he4 = (const float4*)(hE + (size_t)p * D);
            float4 a0 = he4[0], a1 = he4[1], a2 = he4[2], a3 = he4[3];
            float a = tb
                + a0.x * tr[0] + a0.y * tr[1] + a0.z * tr[2] + a0.w * tr[3]
                + a1.x * tr[4] + a1.y * tr[5] + a1.z * tr[6] + a1.w * tr[7]
                + a2.x * tr[8] + a2.y * tr[9] + a2.z * tr[10] + a2.w * tr[11]
                + a3.x * tr[12] + a3.y * tr[13] + a3.z * tr[14] + a3.w * tr[15];
            int q = permInv[p];                 // dst-sorted slot
            msg[(size_t)q * D + o] = a;         // scattered 64B-row store (fire-and-forget)
        }
    }
}

// ---------------- per-layer: dst aggregation (sequential msg read) + root + bias + BN stats ----------------

__global__ void k_agg(const float* __restrict__ h, const float* __restrict__ msg,
                      const int* __restrict__ offsD, const float* __restrict__ root_l,
                      const float* __restrict__ cbias, float* __restrict__ hpre,
                      float* __restrict__ statsR, int n) {
    __shared__ float rootS[D * D];
    __shared__ float red[256], red2[256];
    if (threadIdx.x < D * D) rootS[threadIdx.x] = root_l[threadIdx.x];
    __syncthreads();
    int slot = threadIdx.x >> 4, o = threadIdx.x & 15;
    int node = blockIdx.x * 16 + slot;
    float acc = 0.f;
    if (node < n) {
        int p0 = offsD[node], p1 = offsD[node + 1];
        float sum = 0.f;
        int p = p0;
        for (; p + 4 <= p1; p += 4) {           // unrolled: 4 independent loads in flight
            float a0 = msg[(size_t)(p + 0) * D + o];
            float a1 = msg[(size_t)(p + 1) * D + o];
            float a2 = msg[(size_t)(p + 2) * D + o];
            float a3 = msg[(size_t)(p + 3) * D + o];
            sum += (a0 + a1) + (a2 + a3);
        }
        for (; p < p1; p++) sum += msg[(size_t)p * D + o];
        float deg = (float)((p1 - p0) > 1 ? (p1 - p0) : 1);
        float r = cbias[o];
        const float* hr = h + (size_t)node * D;
#pragma unroll
        for (int i = 0; i < D; i++) r += hr[i] * rootS[i * D + o];
        acc = sum / deg + r;
        hpre[(size_t)node * D + o] = acc;
    }
    red[threadIdx.x] = acc;
    red2[threadIdx.x] = acc * acc;
    __syncthreads();
    for (int off = 128; off >= 16; off >>= 1) {
        if (threadIdx.x < off) {
            red[threadIdx.x] += red[threadIdx.x + off];
            red2[threadIdx.x] += red2[threadIdx.x + off];
        }
        __syncthreads();
    }
    if (threadIdx.x < 32) {
        float v = (threadIdx.x < 16) ? red[threadIdx.x] : red2[threadIdx.x - 16];
        atomicAdd(&statsR[(blockIdx.x & (NREP - 1)) * 32 + threadIdx.x], v);
    }
}

// ---------------- fused readout: final BN+tanh + hidden write + pool + MLP + log_softmax ----------------

__global__ void k_readout(const float* __restrict__ hpre, const float* __restrict__ statsR,
                          const float* __restrict__ gamma, const float* __restrict__ beta,
                          const int* __restrict__ lengths,
                          const float* __restrict__ w1, const float* __restrict__ b1,
                          const float* __restrict__ w2, const float* __restrict__ b2,
                          float* __restrict__ outHidden, float* __restrict__ outPooled,
                          float* __restrict__ fcOut, float* __restrict__ lsmOut,
                          int Gc, int n) {
    __shared__ int sl[512];
    __shared__ float sstats[32];
    int tid = threadIdx.x;
    int g = blockIdx.x;
    if (tid < 32) {
        float a = 0.f;
#pragma unroll 8
        for (int r = 0; r < NREP; r++) a += statsR[r * 32 + tid];
        sstats[tid] = a;
    }
    // redundant per-block scan of lengths (Gc <= 512)
    int v = (tid < Gc) ? lengths[tid] : 0;
    sl[tid] = v;
    __syncthreads();
    for (int d = 1; d < 512; d <<= 1) {
        int t = (tid >= d) ? sl[tid - d] : 0;
        __syncthreads();
        sl[tid] += t;
        __syncthreads();
    }
    int n1 = sl[g];
    int n0 = n1 - lengths[g];
    float fn = (float)n;
    // pool: 32 slots x 16 channels; apply final BN+tanh inline, write hidden
    int slot = tid >> 4, o = tid & 15;
    float mu = sstats[o] / fn;
    float var = sstats[16 + o] / fn - mu * mu;
    float rstd = rsqrtf(var + 1e-5f);
    float gm = gamma[o], bt = beta[o];
    float s = 0.f, mx = -3.402823466e38f, mn = 3.402823466e38f;
    for (int nd = n0 + slot; nd < n1; nd += 32) {
        float xin = hpre[(size_t)nd * D + o];
        float x = tanhf((xin - mu) * rstd * gm + bt);
        outHidden[(size_t)nd * D + o] = x;
        s += x;
        mx = fmaxf(mx, x);
        mn = fminf(mn, x);
    }
    __shared__ float rs[512], rmx[512], rmn[512];
    rs[tid] = s; rmx[tid] = mx; rmn[tid] = mn;
    __syncthreads();
    for (int off = 256; off >= 16; off >>= 1) {
        if (tid < off) {
            rs[tid] += rs[tid + off];
            rmx[tid] = fmaxf(rmx[tid], rmx[tid + off]);
            rmn[tid] = fminf(rmn[tid], rmn[tid + off]);
        }
        __syncthreads();
    }
    __shared__ float p64[64], t16[16], f10[10];
    __shared__ float mred, lred;
    if (tid < 16) {
        float cnt = fmaxf((float)(n1 - n0), 1.f);
        float sum = rs[tid];
        float* row = outPooled + (size_t)g * 64;
        float mean = sum / cnt;
        p64[tid] = mean;          row[tid] = mean;
        p64[16 + tid] = rmx[tid]; row[16 + tid] = rmx[tid];
        p64[32 + tid] = rmn[tid]; row[32 + tid] = rmn[tid];
        p64[48 + tid] = sum;      row[48 + tid] = sum;
    }
    __syncthreads();
    if (tid < 16) {
        float a = b1[tid];
        for (int k = 0; k < 64; k++) a += p64[k] * w1[k * 16 + tid];
        t16[tid] = tanhf(a);
    }
    __syncthreads();
    if (tid < 10) {
        float a = b2[tid];
        for (int oo = 0; oo < 16; oo++) a += t16[oo] * w2[oo * 10 + tid];
        f10[tid] = a;
        fcOut[(size_t)g * 10 + tid] = a;
    }
    __syncthreads();
    if (tid == 0) {
        float m = f10[0];
        for (int c = 1; c < 10; c++) m = fmaxf(m, f10[c]);
        float se = 0.f;
        for (int c = 0; c < 10; c++) se += expf(f10[c] - m);
        mred = m;
        lred = logf(se);
    }
    __syncthreads();
    if (tid < 10)
        lsmOut[(size_t)g * 10 + tid] = f10[tid] - mred - lred;
}

// ---------------- host ----------------

extern "C" void kernel_launch(void* const* d_in, const int* in_sizes, int n_in,
                              void* d_out, int out_size, void* d_ws, size_t ws_size,
                              hipStream_t stream) {
    const float* x    = (const float*)d_in[0];
    const float* ea   = (const float*)d_in[1];
    const float* ew1  = (const float*)d_in[2];
    const float* eb1  = (const float*)d_in[3];
    const float* ew2  = (const float*)d_in[4];
    const float* eb2  = (const float*)d_in[5];
    const float* root = (const float*)d_in[6];
    const float* cb   = (const float*)d_in[7];
    const float* gam  = (const float*)d_in[8];
    const float* bet  = (const float*)d_in[9];
    const float* f1w  = (const float*)d_in[10];
    const float* f1b  = (const float*)d_in[11];
    const float* f2w  = (const float*)d_in[12];
    const float* f2b  = (const float*)d_in[13];
    const int* eidx   = (const int*)d_in[14];
    const int* lens   = (const int*)d_in[15];

    int N  = in_sizes[0] / D;
    int E_ = in_sizes[1] / EFD;
    int Gc = in_sizes[15];
    const int* srcIdx = eidx;
    const int* dstIdx = eidx + E_;

    float* outHidden = (float*)d_out;
    float* outPooled = outHidden + (size_t)N * D;
    float* outFc     = outPooled + (size_t)Gc * 4 * D;
    float* outLsm    = outFc + (size_t)Gc * 10;

    char* wsp = (char*)d_ws;
    size_t off = 0;
    auto alloc = [&](size_t bytes) -> void* {
        void* p = wsp + off;
        off = (off + bytes + 255) & ~(size_t)255;
        return p;
    };
    int*   cnt2    = (int*)alloc((size_t)2 * N * 4);          // cntS | cntD
    int*   offs2   = (int*)alloc((size_t)2 * (N + 1) * 4);    // offsS | offsD
    int*   bsum2   = (int*)alloc(128 * 4);
    int*   rankS   = (int*)alloc((size_t)E_ * 4);
    int*   rankD   = (int*)alloc((size_t)E_ * 4);
    int*   permInv = (int*)alloc((size_t)E_ * 4);
    float* hE      = (float*)alloc((size_t)E_ * D * 4);
    float* msg     = (float*)alloc((size_t)E_ * D * 4);
    float* bufA    = (float*)alloc((size_t)N * D * 4);
    float* tmp     = (float*)alloc((size_t)N * D * 4);
    float* statsR3 = (float*)alloc((size_t)3 * NREP * 32 * 4); // one slot per layer

    int* offsS = offs2;
    int* offsD = offs2 + (N + 1);
    int nScan = (N + 1023) / 1024;

    k_zero2<<<(2 * N + 255) / 256, 256, 0, stream>>>(cnt2, 2 * N, statsR3, 3 * NREP * 32);
    k_rank2<<<(E_ + 255) / 256, 256, 0, stream>>>(srcIdx, dstIdx, cnt2, cnt2 + N,
                                                  rankS, rankD, E_);
    k_scanA2<<<2 * nScan, 1024, 0, stream>>>(cnt2, offs2, bsum2, N, nScan);
    k_scanC2<<<2 * nScan, 1024, 0, stream>>>(offs2, bsum2, N, nScan, E_);
    k_place_he<<<(E_ + 255) / 256, 256, 0, stream>>>(srcIdx, dstIdx, rankS, rankD,
                                                     offsS, offsD, ea, ew1, eb1,
                                                     hE, permInv, E_);

    for (int l = 0; l < 3; l++) {
        const float* hin   = (l == 0) ? x : tmp;   // x or hpre of prev layer
        const float* hroot = (l == 0) ? x : bufA;  // post-BN h for root term
        float* statsCur = statsR3 + (size_t)l * NREP * 32;
        const float* statsPrev = statsR3 + (size_t)(l - 1) * NREP * 32;
        k_Tmsg<<<(N + 15) / 16, 256, 0, stream>>>(
            hin, (l == 0) ? nullptr : statsPrev,
            (l == 0) ? nullptr : gam + (size_t)(l - 1) * 16,
            (l == 0) ? nullptr : bet + (size_t)(l - 1) * 16,
            bufA, ew2, eb2, hE, offsS, permInv, msg, N, (l == 0) ? 0 : 1);
        k_agg<<<(N + 15) / 16, 256, 0, stream>>>(hroot, msg, offsD,
                                                 root + (size_t)l * 256, cb + (size_t)l * 16,
                                                 tmp, statsCur, N);
    }

    k_readout<<<Gc, 512, 0, stream>>>(tmp, statsR3 + (size_t)2 * NREP * 32,
                                      gam + 32, bet + 32, lens, f1w, f1b, f2w, f2b,
                                      outHidden, outPooled, outFc, outLsm, Gc, N);
}

// Round 7
// 332.431 us; speedup vs baseline: 1.9147x; 1.1190x over previous
//
#include <hip/hip_runtime.h>

#define D 16
#define EFD 8
#define NREP 64       // BN-stats replica buffers (breaks atomic same-line contention)
#define TSTRIDE 272   // Tt row: 256 T values + 16 bias; 272%32==16 -> 2-way LDS aliasing (free)

// ---------------- zero scratch (cnt arrays + all 3 BN stat slots) ----------------

__global__ void k_zero2(int* a, int na, float* b, int nb) {
    int i = blockIdx.x * 256 + threadIdx.x;
    if (i < na) a[i] = 0;
    if (i < nb) b[i] = 0.f;
}

// ---------------- rank: one atomic per edge per side; cnt becomes the histogram ----------------

__global__ void k_rank2(const int* __restrict__ src, const int* __restrict__ dst,
                        int* __restrict__ cntS, int* __restrict__ cntD,
                        int* __restrict__ rankS, int* __restrict__ rankD, int E_) {
    int e = blockIdx.x * 256 + threadIdx.x;
    if (e < E_) {
        rankS[e] = atomicAdd(&cntS[src[e]], 1);
        rankD[e] = atomicAdd(&cntD[dst[e]], 1);
    }
}

// ---------------- scans over cntS|cntD (both halves in one launch) ----------------

__global__ void k_scanA2(const int* __restrict__ cnt2, int* __restrict__ offs2,
                         int* __restrict__ bsum2, int n, int nScan) {
    __shared__ int s[1024];
    int half = blockIdx.x / nScan;
    int blk  = blockIdx.x % nScan;
    const int* c = cnt2 + (size_t)half * n;
    int* of = offs2 + (size_t)half * (n + 1);
    int* bs = bsum2 + half * 64;
    int i = blk * 1024 + threadIdx.x;
    int v = (i < n) ? c[i] : 0;
    s[threadIdx.x] = v;
    __syncthreads();
    for (int d = 1; d < 1024; d <<= 1) {
        int t = (threadIdx.x >= d) ? s[threadIdx.x - d] : 0;
        __syncthreads();
        s[threadIdx.x] += t;
        __syncthreads();
    }
    int incl = s[threadIdx.x];
    if (i < n) of[i] = incl - v;            // exclusive within chunk
    if (threadIdx.x == 1023) bs[blk] = incl;
}

// scanC with the 64-entry block-sum scan folded in (done redundantly per block)
__global__ void k_scanC2(int* __restrict__ offs2, const int* __restrict__ bsum2,
                         int n, int nScan, int total) {
    __shared__ int s[64];
    int half = blockIdx.x / nScan;
    int blk  = blockIdx.x % nScan;
    int* of = offs2 + (size_t)half * (n + 1);
    const int* bs = bsum2 + half * 64;
    if (threadIdx.x < 64) s[threadIdx.x] = (threadIdx.x < nScan) ? bs[threadIdx.x] : 0;
    __syncthreads();
    if (threadIdx.x < 64) {
        for (int d = 1; d < 64; d <<= 1) {
            int t = (threadIdx.x >= d) ? s[threadIdx.x - d] : 0;
            __syncthreads();
            s[threadIdx.x] += t;
            __syncthreads();
        }
    } else {
        for (int d = 1; d < 64; d <<= 1) { __syncthreads(); __syncthreads(); }
    }
    int base = (blk == 0) ? 0 : s[blk - 1];
    int i = blk * 1024 + threadIdx.x;
    if (i < n) of[i] += base;
    else if (i == n) of[n] = total;
}

// ---------------- fused place + edge-MLP + permInv: NO atomics ----------------

__global__ void k_place_he(const int* __restrict__ src, const int* __restrict__ dst,
                           const int* __restrict__ rankS, const int* __restrict__ rankD,
                           const int* __restrict__ offsS, const int* __restrict__ offsD,
                           const float* __restrict__ ea, const float* __restrict__ w1,
                           const float* __restrict__ b1,
                           float* __restrict__ hE, int* __restrict__ permInv, int E_) {
    __shared__ float w1s[EFD * D];
    __shared__ float b1s[D];
    if (threadIdx.x < EFD * D) w1s[threadIdx.x] = w1[threadIdx.x];
    if (threadIdx.x < D) b1s[threadIdx.x] = b1[threadIdx.x];
    __syncthreads();
    int e = blockIdx.x * 256 + threadIdx.x;
    if (e >= E_) return;
    int p = offsS[src[e]] + rankS[e];
    int q = offsD[dst[e]] + rankD[e];
    permInv[p] = q;
    const float4* a4 = (const float4*)(ea + (size_t)e * EFD);
    float4 x0 = a4[0], x1 = a4[1];
    float out[D];
#pragma unroll
    for (int o = 0; o < D; o++) {
        float s = b1s[o];
        s += x0.x * w1s[0 * D + o] + x0.y * w1s[1 * D + o] +
             x0.z * w1s[2 * D + o] + x0.w * w1s[3 * D + o] +
             x1.x * w1s[4 * D + o] + x1.y * w1s[5 * D + o] +
             x1.z * w1s[6 * D + o] + x1.w * w1s[7 * D + o];
        out[o] = tanhf(s);
    }
    float4* h4 = (float4*)(hE + (size_t)p * D);
#pragma unroll
    for (int v = 0; v < 4; v++)
        h4[v] = make_float4(out[v * 4 + 0], out[v * 4 + 1], out[v * 4 + 2], out[v * 4 + 3]);
}

// ---------------- per-layer FUSED: [BN+tanh prev] + T-tile (registers+LDS) + messages ----------------
// Block owns 16 src nodes. Thread (j,o) holds w2 column in 16 VGPRs; hs rows read as
// broadcast ds_read_b128. Tt lives in LDS only. Messages written dst-sorted.

__global__ void k_Tmsg(const float* __restrict__ hin, const float* __restrict__ statsPrev,
                       const float* __restrict__ gamma, const float* __restrict__ beta,
                       float* __restrict__ hout, const float* __restrict__ w2,
                       const float* __restrict__ b2, const float* __restrict__ hE,
                       const int* __restrict__ offsS, const int* __restrict__ permInv,
                       float* __restrict__ msg, int n, int useBN) {
    __shared__ float hs[16 * D];          // 16 nodes x 16 feat
    __shared__ float Tt[16 * TSTRIDE];    // [slot][j*16+o | 256+o]
    __shared__ float sstats[32];
    int tid = threadIdx.x;
    int j = tid >> 4, o = tid & 15;
    // per-thread weight columns in registers (global reads, L1/L2-resident across blocks)
    float w16[16], b16[16];
#pragma unroll
    for (int i = 0; i < 16; i++) w16[i] = w2[j * 256 + i * 16 + o];
#pragma unroll
    for (int i = 0; i < 16; i++) b16[i] = b2[i * 16 + o];
    if (useBN && tid < 32) {
        float a = 0.f;
#pragma unroll 8
        for (int r = 0; r < NREP; r++) a += statsPrev[r * 32 + tid];
        sstats[tid] = a;
    }
    __syncthreads();
    int base = blockIdx.x * 16;
    float fn = (float)n;
    {   // stage h rows (apply BN+tanh of previous layer if needed); thread (j,o) covers node j
        int node = base + j;
        float hv = 0.f;
        if (node < n) {
            float xin = hin[(size_t)node * D + o];
            if (useBN) {
                float mu = sstats[o] / fn;
                float var = sstats[16 + o] / fn - mu * mu;
                hv = tanhf((xin - mu) * rsqrtf(var + 1e-5f) * gamma[o] + beta[o]);
                hout[(size_t)node * D + o] = hv;
            } else {
                hv = xin;
            }
        }
        hs[tid] = hv;   // hs[j*16 + o]
    }
    __syncthreads();
    {   // T-tile: broadcast b128 reads of hs + register FMAs
        const float4* hs4 = (const float4*)hs;
#pragma unroll
        for (int nb = 0; nb < 16; nb++) {
            float4 h0 = hs4[nb * 4 + 0], h1 = hs4[nb * 4 + 1];
            float4 h2 = hs4[nb * 4 + 2], h3 = hs4[nb * 4 + 3];
            float s = h0.x * w16[0]  + h0.y * w16[1]  + h0.z * w16[2]  + h0.w * w16[3]
                    + h1.x * w16[4]  + h1.y * w16[5]  + h1.z * w16[6]  + h1.w * w16[7]
                    + h2.x * w16[8]  + h2.y * w16[9]  + h2.z * w16[10] + h2.w * w16[11]
                    + h3.x * w16[12] + h3.y * w16[13] + h3.z * w16[14] + h3.w * w16[15];
            Tt[nb * TSTRIDE + tid] = s;   // contiguous per wave: conflict-free
        }
        // bias projection for node j (thread (j,o) owns it)
        float4 h0 = hs4[j * 4 + 0], h1 = hs4[j * 4 + 1];
        float4 h2 = hs4[j * 4 + 2], h3 = hs4[j * 4 + 3];
        float s = h0.x * b16[0]  + h0.y * b16[1]  + h0.z * b16[2]  + h0.w * b16[3]
                + h1.x * b16[4]  + h1.y * b16[5]  + h1.z * b16[6]  + h1.w * b16[7]
                + h2.x * b16[8]  + h2.y * b16[9]  + h2.z * b16[10] + h2.w * b16[11]
                + h3.x * b16[12] + h3.y * b16[13] + h3.z * b16[14] + h3.w * b16[15];
        Tt[j * TSTRIDE + 256 + o] = s;
    }
    __syncthreads();
    {   // messages: thread (slot=j, o); T row pulled once into registers
        int slot = j;
        int s = base + slot;
        if (s >= n) return;
        float tr[D];
#pragma unroll
        for (int jj = 0; jj < D; jj++) tr[jj] = Tt[slot * TSTRIDE + jj * 16 + o];
        float tb = Tt[slot * TSTRIDE + 256 + o];
        int p0 = offsS[s], p1 = offsS[s + 1];
        for (int p = p0; p < p1; p++) {
            const float4* he4 = (const float4*)(hE + (size_t)p * D);
            float4 a0 = he4[0], a1 = he4[1], a2 = he4[2], a3 = he4[3];
            float a = tb
                + a0.x * tr[0]  + a0.y * tr[1]  + a0.z * tr[2]  + a0.w * tr[3]
                + a1.x * tr[4]  + a1.y * tr[5]  + a1.z * tr[6]  + a1.w * tr[7]
                + a2.x * tr[8]  + a2.y * tr[9]  + a2.z * tr[10] + a2.w * tr[11]
                + a3.x * tr[12] + a3.y * tr[13] + a3.z * tr[14] + a3.w * tr[15];
            int q = permInv[p];                 // dst-sorted slot
            msg[(size_t)q * D + o] = a;         // scattered 64B-row store (fire-and-forget)
        }
    }
}

// ---------------- per-layer: dst aggregation (sequential msg read) + root + bias + BN stats ----------------

__global__ void k_agg(const float* __restrict__ h, const float* __restrict__ msg,
                      const int* __restrict__ offsD, const float* __restrict__ root_l,
                      const float* __restrict__ cbias, float* __restrict__ hpre,
                      float* __restrict__ statsR, int n) {
    __shared__ float rootS[D * D];
    __shared__ float red[256], red2[256];
    if (threadIdx.x < D * D) rootS[threadIdx.x] = root_l[threadIdx.x];
    __syncthreads();
    int slot = threadIdx.x >> 4, o = threadIdx.x & 15;
    int node = blockIdx.x * 16 + slot;
    float acc = 0.f;
    if (node < n) {
        int p0 = offsD[node], p1 = offsD[node + 1];
        float sum = 0.f;
        int p = p0;
        for (; p + 4 <= p1; p += 4) {           // unrolled: 4 independent loads in flight
            float a0 = msg[(size_t)(p + 0) * D + o];
            float a1 = msg[(size_t)(p + 1) * D + o];
            float a2 = msg[(size_t)(p + 2) * D + o];
            float a3 = msg[(size_t)(p + 3) * D + o];
            sum += (a0 + a1) + (a2 + a3);
        }
        for (; p < p1; p++) sum += msg[(size_t)p * D + o];
        float deg = (float)((p1 - p0) > 1 ? (p1 - p0) : 1);
        float r = cbias[o];
        const float* hr = h + (size_t)node * D;
#pragma unroll
        for (int i = 0; i < D; i++) r += hr[i] * rootS[i * D + o];
        acc = sum / deg + r;
        hpre[(size_t)node * D + o] = acc;
    }
    red[threadIdx.x] = acc;
    red2[threadIdx.x] = acc * acc;
    __syncthreads();
    for (int off = 128; off >= 16; off >>= 1) {
        if (threadIdx.x < off) {
            red[threadIdx.x] += red[threadIdx.x + off];
            red2[threadIdx.x] += red2[threadIdx.x + off];
        }
        __syncthreads();
    }
    if (threadIdx.x < 32) {
        float v = (threadIdx.x < 16) ? red[threadIdx.x] : red2[threadIdx.x - 16];
        atomicAdd(&statsR[(blockIdx.x & (NREP - 1)) * 32 + threadIdx.x], v);
    }
}

// ---------------- fused readout: final BN+tanh + hidden write + pool + MLP + log_softmax ----------------

__global__ void k_readout(const float* __restrict__ hpre, const float* __restrict__ statsR,
                          const float* __restrict__ gamma, const float* __restrict__ beta,
                          const int* __restrict__ lengths,
                          const float* __restrict__ w1, const float* __restrict__ b1,
                          const float* __restrict__ w2, const float* __restrict__ b2,
                          float* __restrict__ outHidden, float* __restrict__ outPooled,
                          float* __restrict__ fcOut, float* __restrict__ lsmOut,
                          int Gc, int n) {
    __shared__ int sl[512];
    __shared__ float sstats[32];
    int tid = threadIdx.x;
    int g = blockIdx.x;
    if (tid < 32) {
        float a = 0.f;
#pragma unroll 8
        for (int r = 0; r < NREP; r++) a += statsR[r * 32 + tid];
        sstats[tid] = a;
    }
    int v = (tid < Gc) ? lengths[tid] : 0;
    sl[tid] = v;
    __syncthreads();
    for (int d = 1; d < 512; d <<= 1) {
        int t = (tid >= d) ? sl[tid - d] : 0;
        __syncthreads();
        sl[tid] += t;
        __syncthreads();
    }
    int n1 = sl[g];
    int n0 = n1 - lengths[g];
    float fn = (float)n;
    int slot = tid >> 4, o = tid & 15;
    float mu = sstats[o] / fn;
    float var = sstats[16 + o] / fn - mu * mu;
    float rstd = rsqrtf(var + 1e-5f);
    float gm = gamma[o], bt = beta[o];
    float s = 0.f, mx = -3.402823466e38f, mn = 3.402823466e38f;
    for (int nd = n0 + slot; nd < n1; nd += 32) {
        float xin = hpre[(size_t)nd * D + o];
        float x = tanhf((xin - mu) * rstd * gm + bt);
        outHidden[(size_t)nd * D + o] = x;
        s += x;
        mx = fmaxf(mx, x);
        mn = fminf(mn, x);
    }
    __shared__ float rs[512], rmx[512], rmn[512];
    rs[tid] = s; rmx[tid] = mx; rmn[tid] = mn;
    __syncthreads();
    for (int off = 256; off >= 16; off >>= 1) {
        if (tid < off) {
            rs[tid] += rs[tid + off];
            rmx[tid] = fmaxf(rmx[tid], rmx[tid + off]);
            rmn[tid] = fminf(rmn[tid], rmn[tid + off]);
        }
        __syncthreads();
    }
    __shared__ float p64[64], t16[16], f10[10];
    __shared__ float mred, lred;
    if (tid < 16) {
        float cnt = fmaxf((float)(n1 - n0), 1.f);
        float sum = rs[tid];
        float* row = outPooled + (size_t)g * 64;
        float mean = sum / cnt;
        p64[tid] = mean;          row[tid] = mean;
        p64[16 + tid] = rmx[tid]; row[16 + tid] = rmx[tid];
        p64[32 + tid] = rmn[tid]; row[32 + tid] = rmn[tid];
        p64[48 + tid] = sum;      row[48 + tid] = sum;
    }
    __syncthreads();
    if (tid < 16) {
        float a = b1[tid];
        for (int k = 0; k < 64; k++) a += p64[k] * w1[k * 16 + tid];
        t16[tid] = tanhf(a);
    }
    __syncthreads();
    if (tid < 10) {
        float a = b2[tid];
        for (int oo = 0; oo < 16; oo++) a += t16[oo] * w2[oo * 10 + tid];
        f10[tid] = a;
        fcOut[(size_t)g * 10 + tid] = a;
    }
    __syncthreads();
    if (tid == 0) {
        float m = f10[0];
        for (int c = 1; c < 10; c++) m = fmaxf(m, f10[c]);
        float se = 0.f;
        for (int c = 0; c < 10; c++) se += expf(f10[c] - m);
        mred = m;
        lred = logf(se);
    }
    __syncthreads();
    if (tid < 10)
        lsmOut[(size_t)g * 10 + tid] = f10[tid] - mred - lred;
}

// ---------------- host ----------------

extern "C" void kernel_launch(void* const* d_in, const int* in_sizes, int n_in,
                              void* d_out, int out_size, void* d_ws, size_t ws_size,
                              hipStream_t stream) {
    const float* x    = (const float*)d_in[0];
    const float* ea   = (const float*)d_in[1];
    const float* ew1  = (const float*)d_in[2];
    const float* eb1  = (const float*)d_in[3];
    const float* ew2  = (const float*)d_in[4];
    const float* eb2  = (const float*)d_in[5];
    const float* root = (const float*)d_in[6];
    const float* cb   = (const float*)d_in[7];
    const float* gam  = (const float*)d_in[8];
    const float* bet  = (const float*)d_in[9];
    const float* f1w  = (const float*)d_in[10];
    const float* f1b  = (const float*)d_in[11];
    const float* f2w  = (const float*)d_in[12];
    const float* f2b  = (const float*)d_in[13];
    const int* eidx   = (const int*)d_in[14];
    const int* lens   = (const int*)d_in[15];

    int N  = in_sizes[0] / D;
    int E_ = in_sizes[1] / EFD;
    int Gc = in_sizes[15];
    const int* srcIdx = eidx;
    const int* dstIdx = eidx + E_;

    float* outHidden = (float*)d_out;
    float* outPooled = outHidden + (size_t)N * D;
    float* outFc     = outPooled + (size_t)Gc * 4 * D;
    float* outLsm    = outFc + (size_t)Gc * 10;

    char* wsp = (char*)d_ws;
    size_t off = 0;
    auto alloc = [&](size_t bytes) -> void* {
        void* p = wsp + off;
        off = (off + bytes + 255) & ~(size_t)255;
        return p;
    };
    int*   cnt2    = (int*)alloc((size_t)2 * N * 4);          // cntS | cntD
    int*   offs2   = (int*)alloc((size_t)2 * (N + 1) * 4);    // offsS | offsD
    int*   bsum2   = (int*)alloc(128 * 4);
    int*   rankS   = (int*)alloc((size_t)E_ * 4);
    int*   rankD   = (int*)alloc((size_t)E_ * 4);
    int*   permInv = (int*)alloc((size_t)E_ * 4);
    float* hE      = (float*)alloc((size_t)E_ * D * 4);
    float* msg     = (float*)alloc((size_t)E_ * D * 4);
    float* bufA    = (float*)alloc((size_t)N * D * 4);
    float* tmp     = (float*)alloc((size_t)N * D * 4);
    float* statsR3 = (float*)alloc((size_t)3 * NREP * 32 * 4); // one slot per layer

    int* offsS = offs2;
    int* offsD = offs2 + (N + 1);
    int nScan = (N + 1023) / 1024;

    k_zero2<<<(2 * N + 255) / 256, 256, 0, stream>>>(cnt2, 2 * N, statsR3, 3 * NREP * 32);
    k_rank2<<<(E_ + 255) / 256, 256, 0, stream>>>(srcIdx, dstIdx, cnt2, cnt2 + N,
                                                  rankS, rankD, E_);
    k_scanA2<<<2 * nScan, 1024, 0, stream>>>(cnt2, offs2, bsum2, N, nScan);
    k_scanC2<<<2 * nScan, 1024, 0, stream>>>(offs2, bsum2, N, nScan, E_);
    k_place_he<<<(E_ + 255) / 256, 256, 0, stream>>>(srcIdx, dstIdx, rankS, rankD,
                                                     offsS, offsD, ea, ew1, eb1,
                                                     hE, permInv, E_);

    for (int l = 0; l < 3; l++) {
        const float* hin   = (l == 0) ? x : tmp;   // x or hpre of prev layer
        const float* hroot = (l == 0) ? x : bufA;  // post-BN h for root term
        float* statsCur = statsR3 + (size_t)l * NREP * 32;
        const float* statsPrev = statsR3 + (size_t)(l - 1) * NREP * 32;
        k_Tmsg<<<(N + 15) / 16, 256, 0, stream>>>(
            hin, (l == 0) ? nullptr : statsPrev,
            (l == 0) ? nullptr : gam + (size_t)(l - 1) * 16,
            (l == 0) ? nullptr : bet + (size_t)(l - 1) * 16,
            bufA, ew2, eb2, hE, offsS, permInv, msg, N, (l == 0) ? 0 : 1);
        k_agg<<<(N + 15) / 16, 256, 0, stream>>>(hroot, msg, offsD,
                                                 root + (size_t)l * 256, cb + (size_t)l * 16,
                                                 tmp, statsCur, N);
    }

    k_readout<<<Gc, 512, 0, stream>>>(tmp, statsR3 + (size_t)2 * NREP * 32,
                                      gam + 32, bet + 32, lens, f1w, f1b, f2w, f2b,
                                      outHidden, outPooled, outFc, outLsm, Gc, N);
}